// Round 1
// baseline (1198.259 us; speedup 1.0000x reference)
//
#include <hip/hip_runtime.h>

// Problem constants
#define DMODEL 1024
#define NHEADS 16
#define HDIM   64
#define SEQ    2048
#define BATCH  2
#define MROWS  (SEQ*BATCH)   // 4096

// ---------------------------------------------------------------------------
// GEMM: C = A (M x 1024) @ W^T (W is N x 1024 row-major) + bias
// OUT_MODE 0: write to [B][NHEADS][SEQ][HDIM]  (row m = s*BATCH+b, col n = h*64+d)
// OUT_MODE 1: write plain row-major M x 1024 (final output)
// 64x64 tile, 256 threads, 4x4 per thread, K-tile 16, transposed LDS (+4 pad).
// ---------------------------------------------------------------------------
template <int OUT_MODE>
__global__ __launch_bounds__(256) void gemm_bias_kernel(
    const float* __restrict__ A, const float* __restrict__ W,
    const float* __restrict__ bias, float* __restrict__ C)
{
    __shared__ float sA[16][68];   // [k][m-row]
    __shared__ float sB[16][68];   // [k][n-row]

    const int tid = threadIdx.x;
    const int n0  = blockIdx.x * 64;
    const int m0  = blockIdx.y * 64;
    const int tx  = tid & 15;
    const int ty  = tid >> 4;
    const int ci  = ty * 4;        // local C row
    const int cj  = tx * 4;        // local C col

    const int lrow = tid >> 2;         // 0..63
    const int lk   = (tid & 3) * 4;    // 0,4,8,12

    float acc[4][4] = {};

    for (int k0 = 0; k0 < 1024; k0 += 16) {
        float4 av = *(const float4*)&A[(size_t)(m0 + lrow) * 1024 + k0 + lk];
        float4 wv = *(const float4*)&W[(size_t)(n0 + lrow) * 1024 + k0 + lk];
        __syncthreads();   // protect previous iteration's LDS reads
        sA[lk + 0][lrow] = av.x; sA[lk + 1][lrow] = av.y;
        sA[lk + 2][lrow] = av.z; sA[lk + 3][lrow] = av.w;
        sB[lk + 0][lrow] = wv.x; sB[lk + 1][lrow] = wv.y;
        sB[lk + 2][lrow] = wv.z; sB[lk + 3][lrow] = wv.w;
        __syncthreads();

        #pragma unroll
        for (int kk = 0; kk < 16; ++kk) {
            const float4 a = *(const float4*)&sA[kk][ci];
            const float4 b = *(const float4*)&sB[kk][cj];
            const float ax[4] = {a.x, a.y, a.z, a.w};
            const float bx[4] = {b.x, b.y, b.z, b.w};
            #pragma unroll
            for (int r = 0; r < 4; ++r)
                #pragma unroll
                for (int c = 0; c < 4; ++c)
                    acc[r][c] += ax[r] * bx[c];
        }
    }

    #pragma unroll
    for (int r = 0; r < 4; ++r) {
        const int m = m0 + ci + r;
        #pragma unroll
        for (int c = 0; c < 4; ++c) {
            const int n = n0 + cj + c;
            const float val = acc[r][c] + bias[n];
            if (OUT_MODE == 0) {
                const int s = m >> 1;           // m = s*BATCH + b, BATCH=2
                const int b = m & 1;
                const int h = n >> 6;           // n = h*64 + d
                const int d = n & 63;
                C[(((size_t)(b * NHEADS + h) * SEQ + s) * HDIM) + d] = val;
            } else {
                C[(size_t)m * 1024 + n] = val;
            }
        }
    }
}

// ---------------------------------------------------------------------------
// RoPE in-place on q_r / k_r, layout [B][NHEADS][SEQ][HDIM].
// Reference quirk replicated exactly:
//   out1 = x1*cos - x2*sin ;  out2 = x1*sin - x2*cos   (note the minus!)
// Tables computed in double for accuracy.
// ---------------------------------------------------------------------------
__global__ __launch_bounds__(256) void rope_kernel(float* __restrict__ q,
                                                   float* __restrict__ k)
{
    const int idx = blockIdx.x * 256 + threadIdx.x;   // 0 .. 2^21-1
    const int i  = idx & 31;
    const int s  = (idx >> 5) & 2047;
    const int bh = idx >> 16;                          // 0..31

    const double theta = exp(-(double)i * (9.210340371976184 / 32.0)); // ln(1e4)/32
    double sn_d, cs_d;
    sincos((double)s * theta, &sn_d, &cs_d);
    const float sn = (float)sn_d;
    const float cs = (float)cs_d;

    float* p = (blockIdx.y == 0) ? q : k;
    const size_t base = ((size_t)bh * SEQ + s) * HDIM + i;
    const float x1 = p[base];
    const float x2 = p[base + 32];
    p[base]      = x1 * cs - x2 * sn;
    p[base + 32] = x1 * sn - x2 * cs;
}

// ---------------------------------------------------------------------------
// Flash-style attention. One block = one (bh, 64-row Q tile).
// Online softmax state (m, l) replicated per 16-lane tx-group in registers;
// reductions via __shfl_xor. P reuses the K LDS buffer. No mask.
// Writes attention output in (S, B, DMODEL) layout for the final GEMM.
// ---------------------------------------------------------------------------
__global__ __launch_bounds__(256) void attn_kernel(
    const float* __restrict__ Qr, const float* __restrict__ Kr,
    const float* __restrict__ Vr, float* __restrict__ Out)
{
    __shared__ float sQ[64][68];   // [d][i]  (transposed, pre-scaled)
    __shared__ float sK[64][68];   // [d][j]  ; reused as sP[j][i]
    __shared__ float sV[64][68];   // [j][c]

    const int tid = threadIdx.x;
    const int qt  = blockIdx.x;    // 0..31 q tile
    const int bh  = blockIdx.y;    // 0..31 = b*16+h
    const int tx  = tid & 15;
    const int ty  = tid >> 4;
    const int i0  = ty * 4;        // local q rows
    const int j0  = tx * 4;        // local k cols (scores) / head-dim cols (O)

    const size_t base  = (size_t)bh * SEQ * HDIM;
    const size_t qbase = base + (size_t)qt * 64 * HDIM;

    // stage Q (transposed, scaled by 1/sqrt(64))
    #pragma unroll
    for (int rep = 0; rep < 4; ++rep) {
        const int f   = tid + rep * 256;
        const int row = f >> 4;
        const int d0  = (f & 15) << 2;
        const float4 qv = *(const float4*)&Qr[qbase + (size_t)row * 64 + d0];
        sQ[d0 + 0][row] = qv.x * 0.125f;
        sQ[d0 + 1][row] = qv.y * 0.125f;
        sQ[d0 + 2][row] = qv.z * 0.125f;
        sQ[d0 + 3][row] = qv.w * 0.125f;
    }

    float O[4][4] = {};
    float m_i[4], l_i[4];
    #pragma unroll
    for (int r = 0; r < 4; ++r) { m_i[r] = -INFINITY; l_i[r] = 0.0f; }

    for (int kt = 0; kt < SEQ / 64; ++kt) {
        __syncthreads();   // previous tile's P/V reads done; Q staged (first iter)
        const size_t kbase = base + (size_t)kt * 64 * HDIM;
        #pragma unroll
        for (int rep = 0; rep < 4; ++rep) {
            const int f   = tid + rep * 256;
            const int row = f >> 4;
            const int c0  = (f & 15) << 2;
            const float4 kv = *(const float4*)&Kr[kbase + (size_t)row * 64 + c0];
            sK[c0 + 0][row] = kv.x;
            sK[c0 + 1][row] = kv.y;
            sK[c0 + 2][row] = kv.z;
            sK[c0 + 3][row] = kv.w;
            const float4 vv = *(const float4*)&Vr[kbase + (size_t)row * 64 + c0];
            *(float4*)&sV[row][c0] = vv;
        }
        __syncthreads();

        // S = Q K^T  (scaled already via Q)
        float s4[4][4] = {};
        #pragma unroll 16
        for (int d = 0; d < 64; ++d) {
            const float4 a = *(const float4*)&sQ[d][i0];
            const float4 b = *(const float4*)&sK[d][j0];
            const float ax[4] = {a.x, a.y, a.z, a.w};
            const float bx[4] = {b.x, b.y, b.z, b.w};
            #pragma unroll
            for (int r = 0; r < 4; ++r)
                #pragma unroll
                for (int c = 0; c < 4; ++c)
                    s4[r][c] += ax[r] * bx[c];
        }

        // online softmax (state replicated across the 16-lane tx-group)
        float p4[4][4];
        float alpha[4];
        #pragma unroll
        for (int r = 0; r < 4; ++r) {
            float tm = fmaxf(fmaxf(s4[r][0], s4[r][1]), fmaxf(s4[r][2], s4[r][3]));
            tm = fmaxf(tm, __shfl_xor(tm, 1));
            tm = fmaxf(tm, __shfl_xor(tm, 2));
            tm = fmaxf(tm, __shfl_xor(tm, 4));
            tm = fmaxf(tm, __shfl_xor(tm, 8));
            const float m_new = fmaxf(m_i[r], tm);
            alpha[r] = __expf(m_i[r] - m_new);   // exp(-inf)=0 on first tile
            float rs = 0.0f;
            #pragma unroll
            for (int c = 0; c < 4; ++c) {
                p4[r][c] = __expf(s4[r][c] - m_new);
                rs += p4[r][c];
            }
            rs += __shfl_xor(rs, 1);
            rs += __shfl_xor(rs, 2);
            rs += __shfl_xor(rs, 4);
            rs += __shfl_xor(rs, 8);
            l_i[r] = l_i[r] * alpha[r] + rs;
            m_i[r] = m_new;
        }

        __syncthreads();   // everyone done reading sK as K
        // write P transposed into sK:  sP[j][i]
        #pragma unroll
        for (int r = 0; r < 4; ++r) {
            #pragma unroll
            for (int c = 0; c < 4; ++c)
                sK[j0 + c][i0 + r] = p4[r][c];
            #pragma unroll
            for (int c = 0; c < 4; ++c)
                O[r][c] *= alpha[r];
        }
        __syncthreads();

        // O += P V
        #pragma unroll 16
        for (int j = 0; j < 64; ++j) {
            const float4 p = *(const float4*)&sK[j][i0];
            const float4 v = *(const float4*)&sV[j][j0];
            const float px[4] = {p.x, p.y, p.z, p.w};
            const float vx[4] = {v.x, v.y, v.z, v.w};
            #pragma unroll
            for (int r = 0; r < 4; ++r)
                #pragma unroll
                for (int c = 0; c < 4; ++c)
                    O[r][c] += px[r] * vx[c];
        }
    }

    // epilogue: O / l, write to (S, B, DMODEL)
    const int b = bh >> 4;
    const int h = bh & 15;
    #pragma unroll
    for (int r = 0; r < 4; ++r) {
        const float inv = 1.0f / l_i[r];
        const int sg = qt * 64 + i0 + r;
        float4 o;
        o.x = O[r][0] * inv; o.y = O[r][1] * inv;
        o.z = O[r][2] * inv; o.w = O[r][3] * inv;
        *(float4*)&Out[((size_t)sg * BATCH + b) * DMODEL + h * 64 + j0] = o;
    }
}

// ---------------------------------------------------------------------------
extern "C" void kernel_launch(void* const* d_in, const int* in_sizes, int n_in,
                              void* d_out, int out_size, void* d_ws, size_t ws_size,
                              hipStream_t stream)
{
    const float* query = (const float*)d_in[0];
    const float* key   = (const float*)d_in[1];
    const float* value = (const float*)d_in[2];
    const float* Wq    = (const float*)d_in[3];
    const float* bq    = (const float*)d_in[4];
    const float* Wk    = (const float*)d_in[5];
    const float* bk    = (const float*)d_in[6];
    const float* Wv    = (const float*)d_in[7];
    const float* bv    = (const float*)d_in[8];
    const float* Wo    = (const float*)d_in[9];
    const float* bo    = (const float*)d_in[10];
    float* out = (float*)d_out;

    const size_t TEN = (size_t)MROWS * DMODEL;   // 4,194,304 floats
    float* ws   = (float*)d_ws;
    float* q_r  = ws;            // [B][H][S][Dh]
    float* k_r  = ws + TEN;
    float* v_r  = ws + 2 * TEN;
    float* attn = ws + 3 * TEN;  // (S, B, DMODEL)

    const dim3 gblk(DMODEL / 64, MROWS / 64);   // (16, 64)

    // Q/K/V projections (+bias), written directly to [B][H][S][Dh]
    gemm_bias_kernel<0><<<gblk, 256, 0, stream>>>(query, Wq, bq, q_r);
    gemm_bias_kernel<0><<<gblk, 256, 0, stream>>>(key,   Wk, bk, k_r);
    gemm_bias_kernel<0><<<gblk, 256, 0, stream>>>(value, Wv, bv, v_r);

    // RoPE in-place on q_r and k_r
    rope_kernel<<<dim3((BATCH * NHEADS * SEQ * 32) / 256, 2), 256, 0, stream>>>(q_r, k_r);

    // attention
    attn_kernel<<<dim3(SEQ / 64, BATCH * NHEADS), 256, 0, stream>>>(q_r, k_r, v_r, attn);

    // output projection
    gemm_bias_kernel<1><<<gblk, 256, 0, stream>>>(attn, Wo, bo, out);
}

// Round 2
// 837.621 us; speedup vs baseline: 1.4306x; 1.4306x over previous
//
#include <hip/hip_runtime.h>

// Problem constants
#define DMODEL 1024
#define NHEADS 16
#define HDIM   64
#define SEQ    2048
#define BATCH  2
#define MROWS  (SEQ*BATCH)   // 4096

typedef unsigned short u16;
typedef __attribute__((ext_vector_type(8))) short bfrag;   // 8 bf16 = 4 VGPRs (MFMA A/B frag)
typedef __attribute__((ext_vector_type(4))) float f32x4;   // MFMA C/D frag

// bf16 split helpers (RTN-even). x ~= hi + lo, |err| ~ 2^-17 * |x|
__device__ __forceinline__ u16 f2bf(float x) {
    unsigned u = __float_as_uint(x);
    return (u16)((u + 0x7fffu + ((u >> 16) & 1u)) >> 16);
}
__device__ __forceinline__ float bf2f(u16 h) {
    return __uint_as_float((unsigned)h << 16);
}

// async global->LDS, 16B per lane; LDS dest = wave-uniform base + lane*16
__device__ __forceinline__ void gload_lds16(const u16* g, u16* l) {
    __builtin_amdgcn_global_load_lds(
        (const __attribute__((address_space(1))) unsigned int*)g,
        (__attribute__((address_space(3))) unsigned int*)l, 16, 0, 0);
}

// ---------------------------------------------------------------------------
// fp32 GEMM (unchanged from R1, known-correct): C = A @ W^T + bias
// OUT_MODE 0: write [B][NHEADS][SEQ][HDIM] ; OUT_MODE 1: row-major M x 1024
// ---------------------------------------------------------------------------
template <int OUT_MODE>
__global__ __launch_bounds__(256) void gemm_bias_kernel(
    const float* __restrict__ A, const float* __restrict__ W,
    const float* __restrict__ bias, float* __restrict__ C)
{
    __shared__ float sA[16][68];
    __shared__ float sB[16][68];

    const int tid = threadIdx.x;
    const int n0  = blockIdx.x * 64;
    const int m0  = blockIdx.y * 64;
    const int tx  = tid & 15;
    const int ty  = tid >> 4;
    const int ci  = ty * 4;
    const int cj  = tx * 4;
    const int lrow = tid >> 2;
    const int lk   = (tid & 3) * 4;

    float acc[4][4] = {};

    for (int k0 = 0; k0 < 1024; k0 += 16) {
        float4 av = *(const float4*)&A[(size_t)(m0 + lrow) * 1024 + k0 + lk];
        float4 wv = *(const float4*)&W[(size_t)(n0 + lrow) * 1024 + k0 + lk];
        __syncthreads();
        sA[lk + 0][lrow] = av.x; sA[lk + 1][lrow] = av.y;
        sA[lk + 2][lrow] = av.z; sA[lk + 3][lrow] = av.w;
        sB[lk + 0][lrow] = wv.x; sB[lk + 1][lrow] = wv.y;
        sB[lk + 2][lrow] = wv.z; sB[lk + 3][lrow] = wv.w;
        __syncthreads();

        #pragma unroll
        for (int kk = 0; kk < 16; ++kk) {
            const float4 a = *(const float4*)&sA[kk][ci];
            const float4 b = *(const float4*)&sB[kk][cj];
            const float ax[4] = {a.x, a.y, a.z, a.w};
            const float bx[4] = {b.x, b.y, b.z, b.w};
            #pragma unroll
            for (int r = 0; r < 4; ++r)
                #pragma unroll
                for (int c = 0; c < 4; ++c)
                    acc[r][c] += ax[r] * bx[c];
        }
    }

    #pragma unroll
    for (int r = 0; r < 4; ++r) {
        const int m = m0 + ci + r;
        #pragma unroll
        for (int c = 0; c < 4; ++c) {
            const int n = n0 + cj + c;
            const float val = acc[r][c] + bias[n];
            if (OUT_MODE == 0) {
                const int s = m >> 1;
                const int b = m & 1;
                const int h = n >> 6;
                const int d = n & 63;
                C[(((size_t)(b * NHEADS + h) * SEQ + s) * HDIM) + d] = val;
            } else {
                C[(size_t)m * 1024 + n] = val;
            }
        }
    }
}

// ---------------------------------------------------------------------------
// RoPE + bf16 hi/lo split. Reads fp32 [b][h][s][d]; writes hi/lo bf16 same
// layout. Reference quirk kept: o1 = x1*cos - x2*sin ; o2 = x1*sin - x2*cos.
// scale is applied pre-split (Q gets 1/sqrt(64)=0.125 -> exact in bf16 split).
// ---------------------------------------------------------------------------
__global__ __launch_bounds__(256) void rope_split_kernel(
    const float* __restrict__ src, u16* __restrict__ dsth, u16* __restrict__ dstl,
    float scale)
{
    const int idx = blockIdx.x * 256 + threadIdx.x;  // 2^21 total
    const int i  = idx & 31;
    const int s  = (idx >> 5) & 2047;
    const int bh = idx >> 16;

    const double theta = exp(-(double)i * (9.210340371976184 / 32.0)); // ln(1e4)/32
    double sn_d, cs_d;
    sincos((double)s * theta, &sn_d, &cs_d);
    const float sn = (float)sn_d;
    const float cs = (float)cs_d;

    const size_t base = ((size_t)bh * SEQ + s) * HDIM + i;
    const float x1 = src[base];
    const float x2 = src[base + 32];
    const float o1 = (x1 * cs - x2 * sn) * scale;
    const float o2 = (x1 * sn - x2 * cs) * scale;
    const u16 h1 = f2bf(o1);
    const u16 h2 = f2bf(o2);
    dsth[base]      = h1;  dstl[base]      = f2bf(o1 - bf2f(h1));
    dsth[base + 32] = h2;  dstl[base + 32] = f2bf(o2 - bf2f(h2));
}

// ---------------------------------------------------------------------------
// V transpose + split: fp32 [b][h][s][d] -> bf16 hi/lo [b][h][d][s]
// (PV MFMA's B operand needs key-contiguous V^T rows). LDS tile transpose.
// ---------------------------------------------------------------------------
__global__ __launch_bounds__(256) void vsplit_kernel(
    const float* __restrict__ V, u16* __restrict__ Th, u16* __restrict__ Tl)
{
    __shared__ float sT[64][65];
    const int bh = blockIdx.y;
    const int st = blockIdx.x;
    const int t  = threadIdx.x;

    const int r16 = t >> 4;
    const int c4  = (t & 15) * 4;
    const size_t base = ((size_t)bh * SEQ + st * 64) * HDIM;
    #pragma unroll
    for (int rep = 0; rep < 4; ++rep) {
        const int row = rep * 16 + r16;
        const float4 v = *(const float4*)&V[base + (size_t)row * 64 + c4];
        sT[row][c4] = v.x; sT[row][c4 + 1] = v.y;
        sT[row][c4 + 2] = v.z; sT[row][c4 + 3] = v.w;
    }
    __syncthreads();

    const int d  = t >> 2;
    const int s0 = (t & 3) * 16;
    const size_t ob = ((size_t)bh * 64 + d) * SEQ + st * 64 + s0;
    __align__(16) u16 hb[16];
    __align__(16) u16 lb[16];
    #pragma unroll
    for (int j = 0; j < 16; ++j) {
        const float x = sT[s0 + j][d];
        const u16 h = f2bf(x);
        hb[j] = h;
        lb[j] = f2bf(x - bf2f(h));
    }
    *(uint4*)&Th[ob]     = *(const uint4*)&hb[0];
    *(uint4*)&Th[ob + 8] = *(const uint4*)&hb[8];
    *(uint4*)&Tl[ob]     = *(const uint4*)&lb[0];
    *(uint4*)&Tl[ob + 8] = *(const uint4*)&lb[8];
}

// ---------------------------------------------------------------------------
// MFMA flash attention, split-bf16.
// Block = (qt, bh): 4 waves x 16 q-rows = 64-row Q tile; K-tiles of 64.
// All LDS tiles use 128B rows with XOR chunk-swizzle slot = chunk ^ (row&7)
// so frag ds_read_b128 are ~conflict-free (row stride 128B = 32 banks).
// Q frags live in registers (pre-scaled by 0.125 in rope_split).
// S = (Qh+Ql)(Kh+Kl): 3 MFMAs; O += (Ph+Pl)(Vh+Vl): 3 MFMAs.
// ---------------------------------------------------------------------------
__global__ __launch_bounds__(256) void attn_mfma_kernel(
    const u16* __restrict__ Qh, const u16* __restrict__ Ql,
    const u16* __restrict__ Kh, const u16* __restrict__ Kl,
    const u16* __restrict__ Vh, const u16* __restrict__ Vl,
    float* __restrict__ Out)
{
    __shared__ u16 sKh[4096], sKl[4096];   // [key][dh]  swizzled
    __shared__ u16 sVh[4096], sVl[4096];   // [dh][key]  swizzled
    __shared__ u16 sPh[4096], sPl[4096];   // [q][key]   swizzled, wave-private rows

    const int tid   = threadIdx.x;
    const int w     = tid >> 6;
    const int lane  = tid & 63;
    const int lrow  = lane & 15;
    const int lquad = lane >> 4;
    const int x7    = lrow & 7;
    const int qt    = blockIdx.x;
    const int bh    = blockIdx.y;

    // Q fragments (registers): A[m=lrow][k=ks*32+lquad*8+j]
    const size_t qg = ((size_t)bh * SEQ + qt * 64 + w * 16 + lrow) * HDIM + lquad * 8;
    bfrag qfh[2], qfl[2];
    qfh[0] = *(const bfrag*)&Qh[qg];      qfh[1] = *(const bfrag*)&Qh[qg + 32];
    qfl[0] = *(const bfrag*)&Ql[qg];      qfl[1] = *(const bfrag*)&Ql[qg + 32];

    // staging: wave w stages one of {sKh,sKl,sVh,sVl}; 8 instrs x 1KB each
    const int srow   = lane >> 3;              // row within 8-row slab
    const int schunk = (lane & 7) ^ srow;      // global 16B chunk (XOR swizzle)
    const u16* gsrc; u16* lbase; size_t istep, ktstep;
    if (w < 2) {
        gsrc  = ((w == 0) ? Kh : Kl) + ((size_t)bh * SEQ + srow) * HDIM + schunk * 8;
        istep = 8 * 64; ktstep = 64 * 64;
        lbase = (w == 0) ? sKh : sKl;
    } else {
        gsrc  = ((w == 2) ? Vh : Vl) + ((size_t)bh * 64 + srow) * SEQ + schunk * 8;
        istep = 8 * 2048; ktstep = 64;
        lbase = (w == 2) ? sVh : sVl;
    }

    // frag read offsets (u16 units), loop-invariant:
    // B-frag: row = g*16+lrow, chunk = ks*4+lquad, slot = chunk ^ (row&7)
    int koff[2][4];
    #pragma unroll
    for (int ks = 0; ks < 2; ++ks)
        #pragma unroll
        for (int g = 0; g < 4; ++g)
            koff[ks][g] = (g * 16 + lrow) * 64 + (((ks * 4 + lquad) ^ x7) * 8);
    // P A-frag: row = w*16+lrow
    int poff[2];
    #pragma unroll
    for (int ks = 0; ks < 2; ++ks)
        poff[ks] = (w * 16 + lrow) * 64 + (((ks * 4 + lquad) ^ x7) * 8);
    // P writes (C-layout): row_l = w*16+lquad*4+r, key = kg*16+lrow
    int pwoff[4][4];
    #pragma unroll
    for (int r = 0; r < 4; ++r)
        #pragma unroll
        for (int kg = 0; kg < 4; ++kg) {
            const int row_l = w * 16 + lquad * 4 + r;
            pwoff[r][kg] = row_l * 64 + (((kg * 2 + (lrow >> 3)) ^ (row_l & 7)) * 8) + x7;
        }

    f32x4 accO[4] = {};
    float m_i[4], l_i[4];
    #pragma unroll
    for (int r = 0; r < 4; ++r) { m_i[r] = -INFINITY; l_i[r] = 0.0f; }

    for (int kt = 0; kt < SEQ / 64; ++kt) {
        __syncthreads();                       // prior tile's LDS reads done
        const u16* g = gsrc + (size_t)kt * ktstep;
        #pragma unroll
        for (int i = 0; i < 8; ++i)
            gload_lds16(g + (size_t)i * istep, lbase + i * 512);
        __syncthreads();                       // drains vmcnt (global_load_lds)

        // ---- S = Q K^T (pre-scaled) ----
        f32x4 accS[4] = {};
        #pragma unroll
        for (int kg = 0; kg < 4; ++kg)
            #pragma unroll
            for (int ks = 0; ks < 2; ++ks) {
                const bfrag kh = *(const bfrag*)&sKh[koff[ks][kg]];
                const bfrag kl = *(const bfrag*)&sKl[koff[ks][kg]];
                accS[kg] = __builtin_amdgcn_mfma_f32_16x16x32_bf16(qfh[ks], kh, accS[kg], 0, 0, 0);
                accS[kg] = __builtin_amdgcn_mfma_f32_16x16x32_bf16(qfl[ks], kh, accS[kg], 0, 0, 0);
                accS[kg] = __builtin_amdgcn_mfma_f32_16x16x32_bf16(qfh[ks], kl, accS[kg], 0, 0, 0);
            }

        // ---- online softmax (rows = lquad*4+r, cols across lrow lanes) ----
        float alpha[4];
        #pragma unroll
        for (int r = 0; r < 4; ++r) {
            float tm = fmaxf(fmaxf(accS[0][r], accS[1][r]), fmaxf(accS[2][r], accS[3][r]));
            tm = fmaxf(tm, __shfl_xor(tm, 1));
            tm = fmaxf(tm, __shfl_xor(tm, 2));
            tm = fmaxf(tm, __shfl_xor(tm, 4));
            tm = fmaxf(tm, __shfl_xor(tm, 8));
            const float mn = fmaxf(m_i[r], tm);
            alpha[r] = __expf(m_i[r] - mn);
            float rs = 0.0f;
            #pragma unroll
            for (int kg = 0; kg < 4; ++kg) {
                const float p = __expf(accS[kg][r] - mn);
                rs += p;
                const u16 ph = f2bf(p);
                sPh[pwoff[r][kg]] = ph;
                sPl[pwoff[r][kg]] = f2bf(p - bf2f(ph));
            }
            rs += __shfl_xor(rs, 1);
            rs += __shfl_xor(rs, 2);
            rs += __shfl_xor(rs, 4);
            rs += __shfl_xor(rs, 8);
            l_i[r] = l_i[r] * alpha[r] + rs;
            m_i[r] = mn;
        }

        // rescale accumulator (C-layout rows match alpha rows)
        #pragma unroll
        for (int dt = 0; dt < 4; ++dt)
            #pragma unroll
            for (int r = 0; r < 4; ++r)
                accO[dt][r] *= alpha[r];

        // ---- O += P V  (P rows are wave-private: no barrier needed) ----
        #pragma unroll
        for (int ks = 0; ks < 2; ++ks) {
            const bfrag pfh = *(const bfrag*)&sPh[poff[ks]];
            const bfrag pfl = *(const bfrag*)&sPl[poff[ks]];
            #pragma unroll
            for (int dt = 0; dt < 4; ++dt) {
                const bfrag vh = *(const bfrag*)&sVh[koff[ks][dt]];
                const bfrag vl = *(const bfrag*)&sVl[koff[ks][dt]];
                accO[dt] = __builtin_amdgcn_mfma_f32_16x16x32_bf16(pfh, vh, accO[dt], 0, 0, 0);
                accO[dt] = __builtin_amdgcn_mfma_f32_16x16x32_bf16(pfh, vl, accO[dt], 0, 0, 0);
                accO[dt] = __builtin_amdgcn_mfma_f32_16x16x32_bf16(pfl, vh, accO[dt], 0, 0, 0);
            }
        }
    }

    // epilogue: O/l -> (S, B, DMODEL)
    const int b = bh >> 4;
    const int h = bh & 15;
    #pragma unroll
    for (int r = 0; r < 4; ++r) {
        const float inv = 1.0f / l_i[r];
        const int sg = qt * 64 + w * 16 + lquad * 4 + r;
        const size_t ob = ((size_t)sg * BATCH + b) * DMODEL + h * 64 + lrow;
        #pragma unroll
        for (int dt = 0; dt < 4; ++dt)
            Out[ob + dt * 16] = accO[dt][r] * inv;
    }
}

// ---------------------------------------------------------------------------
extern "C" void kernel_launch(void* const* d_in, const int* in_sizes, int n_in,
                              void* d_out, int out_size, void* d_ws, size_t ws_size,
                              hipStream_t stream)
{
    const float* query = (const float*)d_in[0];
    const float* key   = (const float*)d_in[1];
    const float* value = (const float*)d_in[2];
    const float* Wq    = (const float*)d_in[3];
    const float* bq    = (const float*)d_in[4];
    const float* Wk    = (const float*)d_in[5];
    const float* bk    = (const float*)d_in[6];
    const float* Wv    = (const float*)d_in[7];
    const float* bv    = (const float*)d_in[8];
    const float* Wo    = (const float*)d_in[9];
    const float* bo    = (const float*)d_in[10];
    float* out = (float*)d_out;

    // 64 MB workspace plan (same footprint as R1) with buffer reuse:
    //  [ 0,16) q_r fp32     -> later Kh[0,8) Kl[8,16)   (after rope_q)
    //  [16,32) k_r fp32     -> later attn fp32          (after rope_k)
    //  [32,48) v_r fp32     -> later Qh[32,40) Ql[40,48) (after vsplit)
    //  [48,64) Vth[48,56) Vtl[56,64)
    char* wsb = (char*)d_ws;
    const size_t MB = 1024 * 1024;
    float* q_r  = (float*)(wsb + 0 * MB);
    float* k_r  = (float*)(wsb + 16 * MB);
    float* v_r  = (float*)(wsb + 32 * MB);
    u16*   Vth  = (u16*)(wsb + 48 * MB);
    u16*   Vtl  = (u16*)(wsb + 56 * MB);
    u16*   Qhp  = (u16*)(wsb + 32 * MB);
    u16*   Qlp  = (u16*)(wsb + 40 * MB);
    u16*   Khp  = (u16*)(wsb + 0 * MB);
    u16*   Klp  = (u16*)(wsb + 8 * MB);
    float* attn = (float*)(wsb + 16 * MB);

    const dim3 gblk(DMODEL / 64, MROWS / 64);   // (16, 64)

    // projections (fp32, unchanged)
    gemm_bias_kernel<0><<<gblk, 256, 0, stream>>>(query, Wq, bq, q_r);
    gemm_bias_kernel<0><<<gblk, 256, 0, stream>>>(key,   Wk, bk, k_r);
    gemm_bias_kernel<0><<<gblk, 256, 0, stream>>>(value, Wv, bv, v_r);

    // V transpose + split (v_r dead after)
    vsplit_kernel<<<dim3(SEQ / 64, BATCH * NHEADS), 256, 0, stream>>>(v_r, Vth, Vtl);
    // RoPE + split; Q pre-scaled by 0.125 (exact). q_r dead after rope_q, etc.
    rope_split_kernel<<<(BATCH * NHEADS * SEQ * 32) / 256, 256, 0, stream>>>(q_r, Qhp, Qlp, 0.125f);
    rope_split_kernel<<<(BATCH * NHEADS * SEQ * 32) / 256, 256, 0, stream>>>(k_r, Khp, Klp, 1.0f);

    // MFMA attention -> (S,B,D) fp32
    attn_mfma_kernel<<<dim3(SEQ / 64, BATCH * NHEADS), 256, 0, stream>>>(
        Qhp, Qlp, Khp, Klp, Vth, Vtl, attn);

    // output projection
    gemm_bias_kernel<1><<<gblk, 256, 0, stream>>>(attn, Wo, bo, out);
}

// Round 3
// 480.294 us; speedup vs baseline: 2.4948x; 1.7440x over previous
//
#include <hip/hip_runtime.h>

// Problem constants
#define DMODEL 1024
#define NHEADS 16
#define HDIM   64
#define SEQ    2048
#define BATCH  2
#define MROWS  (SEQ*BATCH)   // 4096

typedef unsigned short u16;
typedef __attribute__((ext_vector_type(8))) short bfrag;   // 8 bf16 (MFMA A/B frag)
typedef __attribute__((ext_vector_type(4))) float f32x4;   // MFMA C/D frag

// bf16 split helpers (RTN-even). x ~= hi + lo
__device__ __forceinline__ u16 f2bf(float x) {
    unsigned u = __float_as_uint(x);
    return (u16)((u + 0x7fffu + ((u >> 16) & 1u)) >> 16);
}
__device__ __forceinline__ float bf2f(u16 h) {
    return __uint_as_float((unsigned)h << 16);
}

// async global->LDS, 16B/lane; LDS dest is wave-uniform base (+lane*16 by HW)
__device__ __forceinline__ void gload_lds16(const u16* g, u16* l) {
    __builtin_amdgcn_global_load_lds(
        (const __attribute__((address_space(1))) unsigned int*)g,
        (__attribute__((address_space(3))) unsigned int*)l, 16, 0, 0);
}
__device__ __forceinline__ void gload_lds16f(const float* g, float* l) {
    __builtin_amdgcn_global_load_lds(
        (const __attribute__((address_space(1))) unsigned int*)g,
        (__attribute__((address_space(3))) unsigned int*)l, 16, 0, 0);
}

// ---------------------------------------------------------------------------
// Weight split: fp32 -> bf16 hi/lo, elementwise (1M elems per weight)
// ---------------------------------------------------------------------------
__global__ __launch_bounds__(256) void split_kernel(
    const float* __restrict__ src, u16* __restrict__ h, u16* __restrict__ l, int n8)
{
    const int i = blockIdx.x * 256 + threadIdx.x;
    if (i >= n8) return;
    float xs[8];
    *(float4*)&xs[0] = ((const float4*)src)[i * 2];
    *(float4*)&xs[4] = ((const float4*)src)[i * 2 + 1];
    __align__(16) u16 hb[8];
    __align__(16) u16 lb[8];
    #pragma unroll
    for (int j = 0; j < 8; ++j) {
        const u16 hh = f2bf(xs[j]);
        hb[j] = hh;
        lb[j] = f2bf(xs[j] - bf2f(hh));
    }
    *(uint4*)&h[i * 8] = *(const uint4*)hb;
    *(uint4*)&l[i * 8] = *(const uint4*)lb;
}

// ---------------------------------------------------------------------------
// MFMA split-bf16 GEMM: C = A(Mx1024 fp32) @ W^T + bias, W pre-split bf16.
// BM=128, BN=64, BK=64. 4 waves; wave w owns rows [w*32,w*32+32) x all 64 n.
// A staged fp32 in LDS (16-chunk XOR swizzle), split to hi/lo at frag read.
// B staged split bf16 (8-chunk XOR swizzle, proven conflict-free in R2).
// OUT_MODE 0: RoPE(+scale)+split -> [b][h][s][d] bf16 hi/lo (Q/K)
// OUT_MODE 1: split -> [b][h][s][d] bf16 hi/lo (V)
// OUT_MODE 2: fp32 row-major Mx1024 (final output)
// ---------------------------------------------------------------------------
template <int OUT_MODE>
__global__ __launch_bounds__(256) void gemm_mfma_kernel(
    const float* __restrict__ Af,
    const u16* __restrict__ Wh, const u16* __restrict__ Wl,
    const float* __restrict__ bias, float rope_scale,
    u16* __restrict__ Oh, u16* __restrict__ Ol, float* __restrict__ Of)
{
    __shared__ float sAf[8192];   // 128 rows x 64 fp32, swizzled (32KB)
    __shared__ u16 sBh[4096];     // 64 rows x 64 bf16, swizzled (8KB)
    __shared__ u16 sBl[4096];

    const int tid   = threadIdx.x;
    const int w     = tid >> 6;
    const int lane  = tid & 63;
    const int lrow  = lane & 15;
    const int lquad = lane >> 4;
    const int n0    = blockIdx.x * 64;    // = head * 64
    const int m0    = blockIdx.y * 128;

    // staging coords
    const int r4   = lane >> 4;                 // A: row within 4-row slab
    const int s16  = lane & 15;                 // A: dest slot
    const int r8   = lane >> 3;                 // B: row within 8-row slab
    const int sch8 = (lane & 7) ^ (r8 & 7);     // B: global chunk

    // frag read offsets
    int aoff[2][2][2];   // [ks][mi][half] (float units)
    int boff[2][4];      // [ks][ni]       (u16 units)
    #pragma unroll
    for (int ks = 0; ks < 2; ++ks) {
        #pragma unroll
        for (int mi = 0; mi < 2; ++mi) {
            const int ra = w * 32 + mi * 16 + lrow;
            #pragma unroll
            for (int hf = 0; hf < 2; ++hf) {
                const int c = ks * 8 + lquad * 2 + hf;
                aoff[ks][mi][hf] = ra * 64 + ((c ^ (ra & 15)) << 2);
            }
        }
        #pragma unroll
        for (int ni = 0; ni < 4; ++ni) {
            const int rb = ni * 16 + lrow;
            boff[ks][ni] = rb * 64 + (((ks * 4 + lquad) ^ (rb & 7)) << 3);
        }
    }

    f32x4 acc[2][4] = {};

    for (int k0 = 0; k0 < 1024; k0 += 64) {
        __syncthreads();   // prior iteration's LDS reads complete
        // stage A (fp32): 8 slabs of 1KB per wave
        #pragma unroll
        for (int i = 0; i < 8; ++i) {
            const int slab = w * 8 + i;
            const int row  = slab * 4 + r4;
            const int gch  = s16 ^ (row & 15);
            gload_lds16f(Af + (size_t)(m0 + row) * 1024 + k0 + gch * 4,
                         sAf + slab * 256);
        }
        // stage B (split bf16): 2 slabs each of Bh/Bl per wave
        #pragma unroll
        for (int i = 0; i < 2; ++i) {
            const int slab = w * 2 + i;            // 0..7
            const int row  = slab * 8 + r8;
            gload_lds16(Wh + (size_t)(n0 + row) * 1024 + k0 + sch8 * 8,
                        sBh + slab * 512);
            gload_lds16(Wl + (size_t)(n0 + row) * 1024 + k0 + sch8 * 8,
                        sBl + slab * 512);
        }
        __syncthreads();   // drains vmcnt for global_load_lds

        #pragma unroll
        for (int ks = 0; ks < 2; ++ks) {
            bfrag ah[2], al[2], bh[4], bl[4];
            #pragma unroll
            for (int mi = 0; mi < 2; ++mi) {
                float xf[8];
                *(float4*)&xf[0] = *(const float4*)&sAf[aoff[ks][mi][0]];
                *(float4*)&xf[4] = *(const float4*)&sAf[aoff[ks][mi][1]];
                #pragma unroll
                for (int j = 0; j < 8; ++j) {
                    const u16 hh = f2bf(xf[j]);
                    ah[mi][j] = (short)hh;
                    al[mi][j] = (short)f2bf(xf[j] - bf2f(hh));
                }
            }
            #pragma unroll
            for (int ni = 0; ni < 4; ++ni) {
                bh[ni] = *(const bfrag*)&sBh[boff[ks][ni]];
                bl[ni] = *(const bfrag*)&sBl[boff[ks][ni]];
            }
            #pragma unroll
            for (int mi = 0; mi < 2; ++mi)
                #pragma unroll
                for (int ni = 0; ni < 4; ++ni) {
                    acc[mi][ni] = __builtin_amdgcn_mfma_f32_16x16x32_bf16(ah[mi], bh[ni], acc[mi][ni], 0, 0, 0);
                    acc[mi][ni] = __builtin_amdgcn_mfma_f32_16x16x32_bf16(ah[mi], bl[ni], acc[mi][ni], 0, 0, 0);
                    acc[mi][ni] = __builtin_amdgcn_mfma_f32_16x16x32_bf16(al[mi], bh[ni], acc[mi][ni], 0, 0, 0);
                }
        }
    }

    // bias values for this lane's 4 n-columns
    float bn[4];
    #pragma unroll
    for (int ni = 0; ni < 4; ++ni) bn[ni] = bias[n0 + ni * 16 + lrow];

    if (OUT_MODE == 0) {
        // build sincos table in dead staging LDS: 64 s x 32 i (double precision)
        __syncthreads();
        float2* tab = (float2*)sAf;    // 2048 float2 = 16KB
        const int s0b = m0 >> 1;
        for (int e = tid; e < 2048; e += 256) {
            const int sl = e >> 5, i = e & 31;
            const double th = exp(-(double)i * (9.210340371976184 / 32.0));
            double sn, cs;
            sincos((double)(s0b + sl) * th, &sn, &cs);
            tab[e] = make_float2((float)sn, (float)cs);
        }
        __syncthreads();

        const int h = blockIdx.x;     // BN=64 => one head per block
        #pragma unroll
        for (int mi = 0; mi < 2; ++mi)
            #pragma unroll
            for (int r = 0; r < 4; ++r) {
                const int mrow = w * 32 + mi * 16 + lquad * 4 + r;
                const int m  = m0 + mrow;
                const int b  = m & 1;
                const int sg = m >> 1;
                const int sl = mrow >> 1;
                const size_t ob = (((size_t)(b * NHEADS + h) * SEQ) + sg) * HDIM;
                #pragma unroll
                for (int ni = 0; ni < 2; ++ni) {
                    const int i = ni * 16 + lrow;
                    const float2 sc = tab[sl * 32 + i];
                    const float x1 = acc[mi][ni][r]     + bn[ni];
                    const float x2 = acc[mi][ni + 2][r] + bn[ni + 2];
                    // reference quirk: o2 = x1*sin - x2*cos
                    const float o1 = (x1 * sc.y - x2 * sc.x) * rope_scale;
                    const float o2 = (x1 * sc.x - x2 * sc.y) * rope_scale;
                    const u16 h1 = f2bf(o1);
                    const u16 h2 = f2bf(o2);
                    Oh[ob + i]      = h1;  Ol[ob + i]      = f2bf(o1 - bf2f(h1));
                    Oh[ob + i + 32] = h2;  Ol[ob + i + 32] = f2bf(o2 - bf2f(h2));
                }
            }
    } else if (OUT_MODE == 1) {
        const int h = blockIdx.x;
        #pragma unroll
        for (int mi = 0; mi < 2; ++mi)
            #pragma unroll
            for (int r = 0; r < 4; ++r) {
                const int mrow = w * 32 + mi * 16 + lquad * 4 + r;
                const int m  = m0 + mrow;
                const int b  = m & 1;
                const int sg = m >> 1;
                const size_t ob = (((size_t)(b * NHEADS + h) * SEQ) + sg) * HDIM;
                #pragma unroll
                for (int ni = 0; ni < 4; ++ni) {
                    const float v = acc[mi][ni][r] + bn[ni];
                    const u16 hh = f2bf(v);
                    Oh[ob + ni * 16 + lrow] = hh;
                    Ol[ob + ni * 16 + lrow] = f2bf(v - bf2f(hh));
                }
            }
    } else {
        #pragma unroll
        for (int mi = 0; mi < 2; ++mi)
            #pragma unroll
            for (int r = 0; r < 4; ++r) {
                const int m = m0 + w * 32 + mi * 16 + lquad * 4 + r;
                #pragma unroll
                for (int ni = 0; ni < 4; ++ni)
                    Of[(size_t)m * 1024 + n0 + ni * 16 + lrow] = acc[mi][ni][r] + bn[ni];
            }
    }
}

// ---------------------------------------------------------------------------
// V^T: bf16 [b][h][s][d] -> [b][h][d][s], grid.z selects hi/lo buffer
// ---------------------------------------------------------------------------
__global__ __launch_bounds__(256) void vtrans_kernel(
    const u16* __restrict__ Vh, const u16* __restrict__ Vl,
    u16* __restrict__ Th, u16* __restrict__ Tl)
{
    __shared__ u16 sT[64][72];
    const u16* src = blockIdx.z ? Vl : Vh;
    u16* dst       = blockIdx.z ? Tl : Th;
    const int bh = blockIdx.y;
    const int st = blockIdx.x;
    const int tid = threadIdx.x;

    #pragma unroll
    for (int rep = 0; rep < 2; ++rep) {
        const int c = rep * 256 + tid;
        const int row = c >> 3, ch = c & 7;
        *(uint4*)&sT[row][ch * 8] =
            *(const uint4*)&src[((size_t)bh * SEQ + st * 64 + row) * HDIM + ch * 8];
    }
    __syncthreads();
    #pragma unroll
    for (int rep = 0; rep < 2; ++rep) {
        const int c = rep * 256 + tid;
        const int d = c >> 3, s8 = c & 7;
        __align__(16) u16 tmp[8];
        #pragma unroll
        for (int j = 0; j < 8; ++j) tmp[j] = sT[s8 * 8 + j][d];
        *(uint4*)&dst[((size_t)bh * HDIM + d) * SEQ + st * 64 + s8 * 8] = *(const uint4*)tmp;
    }
}

// ---------------------------------------------------------------------------
// MFMA flash attention, split-bf16 (byte-identical to R2's proven kernel)
// ---------------------------------------------------------------------------
__global__ __launch_bounds__(256) void attn_mfma_kernel(
    const u16* __restrict__ Qh, const u16* __restrict__ Ql,
    const u16* __restrict__ Kh, const u16* __restrict__ Kl,
    const u16* __restrict__ Vh, const u16* __restrict__ Vl,
    float* __restrict__ Out)
{
    __shared__ u16 sKh[4096], sKl[4096];   // [key][dh]  swizzled
    __shared__ u16 sVh[4096], sVl[4096];   // [dh][key]  swizzled
    __shared__ u16 sPh[4096], sPl[4096];   // [q][key]   swizzled, wave-private rows

    const int tid   = threadIdx.x;
    const int w     = tid >> 6;
    const int lane  = tid & 63;
    const int lrow  = lane & 15;
    const int lquad = lane >> 4;
    const int x7    = lrow & 7;
    const int qt    = blockIdx.x;
    const int bh    = blockIdx.y;

    const size_t qg = ((size_t)bh * SEQ + qt * 64 + w * 16 + lrow) * HDIM + lquad * 8;
    bfrag qfh[2], qfl[2];
    qfh[0] = *(const bfrag*)&Qh[qg];      qfh[1] = *(const bfrag*)&Qh[qg + 32];
    qfl[0] = *(const bfrag*)&Ql[qg];      qfl[1] = *(const bfrag*)&Ql[qg + 32];

    const int srow   = lane >> 3;
    const int schunk = (lane & 7) ^ srow;
    const u16* gsrc; u16* lbase; size_t istep, ktstep;
    if (w < 2) {
        gsrc  = ((w == 0) ? Kh : Kl) + ((size_t)bh * SEQ + srow) * HDIM + schunk * 8;
        istep = 8 * 64; ktstep = 64 * 64;
        lbase = (w == 0) ? sKh : sKl;
    } else {
        gsrc  = ((w == 2) ? Vh : Vl) + ((size_t)bh * 64 + srow) * SEQ + schunk * 8;
        istep = 8 * 2048; ktstep = 64;
        lbase = (w == 2) ? sVh : sVl;
    }

    int koff[2][4];
    #pragma unroll
    for (int ks = 0; ks < 2; ++ks)
        #pragma unroll
        for (int g = 0; g < 4; ++g)
            koff[ks][g] = (g * 16 + lrow) * 64 + (((ks * 4 + lquad) ^ x7) * 8);
    int poff[2];
    #pragma unroll
    for (int ks = 0; ks < 2; ++ks)
        poff[ks] = (w * 16 + lrow) * 64 + (((ks * 4 + lquad) ^ x7) * 8);
    int pwoff[4][4];
    #pragma unroll
    for (int r = 0; r < 4; ++r)
        #pragma unroll
        for (int kg = 0; kg < 4; ++kg) {
            const int row_l = w * 16 + lquad * 4 + r;
            pwoff[r][kg] = row_l * 64 + (((kg * 2 + (lrow >> 3)) ^ (row_l & 7)) * 8) + x7;
        }

    f32x4 accO[4] = {};
    float m_i[4], l_i[4];
    #pragma unroll
    for (int r = 0; r < 4; ++r) { m_i[r] = -INFINITY; l_i[r] = 0.0f; }

    for (int kt = 0; kt < SEQ / 64; ++kt) {
        __syncthreads();
        const u16* g = gsrc + (size_t)kt * ktstep;
        #pragma unroll
        for (int i = 0; i < 8; ++i)
            gload_lds16(g + (size_t)i * istep, lbase + i * 512);
        __syncthreads();

        f32x4 accS[4] = {};
        #pragma unroll
        for (int kg = 0; kg < 4; ++kg)
            #pragma unroll
            for (int ks = 0; ks < 2; ++ks) {
                const bfrag kh = *(const bfrag*)&sKh[koff[ks][kg]];
                const bfrag kl = *(const bfrag*)&sKl[koff[ks][kg]];
                accS[kg] = __builtin_amdgcn_mfma_f32_16x16x32_bf16(qfh[ks], kh, accS[kg], 0, 0, 0);
                accS[kg] = __builtin_amdgcn_mfma_f32_16x16x32_bf16(qfl[ks], kh, accS[kg], 0, 0, 0);
                accS[kg] = __builtin_amdgcn_mfma_f32_16x16x32_bf16(qfh[ks], kl, accS[kg], 0, 0, 0);
            }

        float alpha[4];
        #pragma unroll
        for (int r = 0; r < 4; ++r) {
            float tm = fmaxf(fmaxf(accS[0][r], accS[1][r]), fmaxf(accS[2][r], accS[3][r]));
            tm = fmaxf(tm, __shfl_xor(tm, 1));
            tm = fmaxf(tm, __shfl_xor(tm, 2));
            tm = fmaxf(tm, __shfl_xor(tm, 4));
            tm = fmaxf(tm, __shfl_xor(tm, 8));
            const float mn = fmaxf(m_i[r], tm);
            alpha[r] = __expf(m_i[r] - mn);
            float rs = 0.0f;
            #pragma unroll
            for (int kg = 0; kg < 4; ++kg) {
                const float p = __expf(accS[kg][r] - mn);
                rs += p;
                const u16 ph = f2bf(p);
                sPh[pwoff[r][kg]] = ph;
                sPl[pwoff[r][kg]] = f2bf(p - bf2f(ph));
            }
            rs += __shfl_xor(rs, 1);
            rs += __shfl_xor(rs, 2);
            rs += __shfl_xor(rs, 4);
            rs += __shfl_xor(rs, 8);
            l_i[r] = l_i[r] * alpha[r] + rs;
            m_i[r] = mn;
        }

        #pragma unroll
        for (int dt = 0; dt < 4; ++dt)
            #pragma unroll
            for (int r = 0; r < 4; ++r)
                accO[dt][r] *= alpha[r];

        #pragma unroll
        for (int ks = 0; ks < 2; ++ks) {
            const bfrag pfh = *(const bfrag*)&sPh[poff[ks]];
            const bfrag pfl = *(const bfrag*)&sPl[poff[ks]];
            #pragma unroll
            for (int dt = 0; dt < 4; ++dt) {
                const bfrag vh = *(const bfrag*)&sVh[koff[ks][dt]];
                const bfrag vl = *(const bfrag*)&sVl[koff[ks][dt]];
                accO[dt] = __builtin_amdgcn_mfma_f32_16x16x32_bf16(pfh, vh, accO[dt], 0, 0, 0);
                accO[dt] = __builtin_amdgcn_mfma_f32_16x16x32_bf16(pfh, vl, accO[dt], 0, 0, 0);
                accO[dt] = __builtin_amdgcn_mfma_f32_16x16x32_bf16(pfl, vh, accO[dt], 0, 0, 0);
            }
        }
    }

    const int b = bh >> 4;
    const int h = bh & 15;
    #pragma unroll
    for (int r = 0; r < 4; ++r) {
        const float inv = 1.0f / l_i[r];
        const int sg = qt * 64 + w * 16 + lquad * 4 + r;
        const size_t ob = ((size_t)sg * BATCH + b) * DMODEL + h * 64 + lrow;
        #pragma unroll
        for (int dt = 0; dt < 4; ++dt)
            Out[ob + dt * 16] = accO[dt][r] * inv;
    }
}

// ---------------------------------------------------------------------------
extern "C" void kernel_launch(void* const* d_in, const int* in_sizes, int n_in,
                              void* d_out, int out_size, void* d_ws, size_t ws_size,
                              hipStream_t stream)
{
    const float* query = (const float*)d_in[0];
    const float* key   = (const float*)d_in[1];
    const float* value = (const float*)d_in[2];
    const float* Wq    = (const float*)d_in[3];
    const float* bq    = (const float*)d_in[4];
    const float* Wk    = (const float*)d_in[5];
    const float* bk    = (const float*)d_in[6];
    const float* Wv    = (const float*)d_in[7];
    const float* bv    = (const float*)d_in[8];
    const float* Wo    = (const float*)d_in[9];
    const float* bo    = (const float*)d_in[10];
    float* out = (float*)d_out;

    // 64 MB workspace, time-multiplexed (MB offsets):
    //  [0,4)   W split slot (Wq->Wk->Wv sequentially)  }  both dead before
    //  [0,16)  V^T split (hi [0,8), lo [8,16))         }  vtrans / after V-GEMM
    //  [16,32) Q split (hi/lo)  -> Wo split [16,20) after attn
    //  [32,48) K split (hi/lo)
    //  [48,64) V split (hi/lo)  -> attn fp32 out [48,64) after vtrans
    char* wsb = (char*)d_ws;
    const size_t MB = 1024 * 1024;
    u16* Wsh = (u16*)(wsb + 0 * MB);
    u16* Wsl = (u16*)(wsb + 2 * MB);
    u16* VTh = (u16*)(wsb + 0 * MB);
    u16* VTl = (u16*)(wsb + 8 * MB);
    u16* Qh  = (u16*)(wsb + 16 * MB);
    u16* Ql  = (u16*)(wsb + 24 * MB);
    u16* Kh  = (u16*)(wsb + 32 * MB);
    u16* Kl  = (u16*)(wsb + 40 * MB);
    u16* Vh  = (u16*)(wsb + 48 * MB);
    u16* Vl  = (u16*)(wsb + 56 * MB);
    float* attnf = (float*)(wsb + 48 * MB);
    u16* Woh = (u16*)(wsb + 16 * MB);
    u16* Wol = (u16*)(wsb + 18 * MB);

    const dim3 ggrid(DMODEL / 64, MROWS / 128);   // (16, 32)
    const int WN8 = DMODEL * DMODEL / 8;          // 131072

    // Q projection (+RoPE, pre-scaled by 1/sqrt(64)) -> split bf16
    split_kernel<<<WN8 / 256, 256, 0, stream>>>(Wq, Wsh, Wsl, WN8);
    gemm_mfma_kernel<0><<<ggrid, 256, 0, stream>>>(query, Wsh, Wsl, bq, 0.125f, Qh, Ql, nullptr);
    // K projection (+RoPE)
    split_kernel<<<WN8 / 256, 256, 0, stream>>>(Wk, Wsh, Wsl, WN8);
    gemm_mfma_kernel<0><<<ggrid, 256, 0, stream>>>(key, Wsh, Wsl, bk, 1.0f, Kh, Kl, nullptr);
    // V projection -> split bf16
    split_kernel<<<WN8 / 256, 256, 0, stream>>>(Wv, Wsh, Wsl, WN8);
    gemm_mfma_kernel<1><<<ggrid, 256, 0, stream>>>(value, Wsh, Wsl, bv, 1.0f, Vh, Vl, nullptr);
    // V^T
    vtrans_kernel<<<dim3(SEQ / 64, BATCH * NHEADS, 2), 256, 0, stream>>>(Vh, Vl, VTh, VTl);
    // attention -> fp32 (S,B,D)
    attn_mfma_kernel<<<dim3(SEQ / 64, BATCH * NHEADS), 256, 0, stream>>>(
        Qh, Ql, Kh, Kl, VTh, VTl, attnf);
    // output projection
    split_kernel<<<WN8 / 256, 256, 0, stream>>>(Wo, Woh, Wol, WN8);
    gemm_mfma_kernel<2><<<ggrid, 256, 0, stream>>>(attnf, Woh, Wol, bo, 1.0f, nullptr, nullptr, out);
}

// Round 4
// 383.467 us; speedup vs baseline: 3.1248x; 1.2525x over previous
//
#include <hip/hip_runtime.h>

// Problem constants
#define DMODEL 1024
#define NHEADS 16
#define HDIM   64
#define SEQ    2048
#define BATCH  2
#define MROWS  (SEQ*BATCH)   // 4096

typedef unsigned int u32;
typedef unsigned short u16;
typedef __attribute__((ext_vector_type(8))) short bfrag;    // 8 bf16 (A/B frag)
typedef __attribute__((ext_vector_type(4))) float f32x4;    // 16x16 C/D frag
typedef __attribute__((ext_vector_type(16))) float f32x16;  // 32x32 C/D frag
typedef union { u32 u[4]; bfrag f; uint4 v4; } fragu;

// bf16 split helpers (RTN-even). x ~= hi + lo
__device__ __forceinline__ u16 f2bf(float x) {
    unsigned u = __float_as_uint(x);
    return (u16)((u + 0x7fffu + ((u >> 16) & 1u)) >> 16);
}
__device__ __forceinline__ float bf2f(u16 h) {
    return __uint_as_float((unsigned)h << 16);
}

// async global->LDS, 16B/lane; LDS dest = wave-uniform base (+lane*16 by HW)
__device__ __forceinline__ void gload_lds16(const u16* g, u16* l) {
    __builtin_amdgcn_global_load_lds(
        (const __attribute__((address_space(1))) unsigned int*)g,
        (__attribute__((address_space(3))) unsigned int*)l, 16, 0, 0);
}
__device__ __forceinline__ void gload_lds16f(const float* g, float* l) {
    __builtin_amdgcn_global_load_lds(
        (const __attribute__((address_space(1))) unsigned int*)g,
        (__attribute__((address_space(3))) unsigned int*)l, 16, 0, 0);
}

// ---------------------------------------------------------------------------
// Prep: split Wq/Wk/Wv (y=0..2) + build f64-accurate RoPE table (y=3).
// ---------------------------------------------------------------------------
__global__ __launch_bounds__(256) void prep_kernel(
    const float* __restrict__ Wq, const float* __restrict__ Wk,
    const float* __restrict__ Wv,
    u16* __restrict__ qh, u16* __restrict__ ql,
    u16* __restrict__ kh, u16* __restrict__ kl,
    u16* __restrict__ vh, u16* __restrict__ vl,
    float2* __restrict__ tab)
{
    const int y = blockIdx.y;
    if (y == 3) {
        if (blockIdx.x >= 256) return;
        const int e = blockIdx.x * 256 + threadIdx.x;   // 65536 = 2048 s x 32 i
        const int s = e >> 5, i = e & 31;
        const double th = exp(-(double)i * (9.210340371976184 / 32.0)); // ln(1e4)/32
        double sn, cs;
        sincos((double)s * th, &sn, &cs);
        tab[e] = make_float2((float)sn, (float)cs);
        return;
    }
    const float* src = (y == 0) ? Wq : (y == 1) ? Wk : Wv;
    u16* dh = (y == 0) ? qh : (y == 1) ? kh : vh;
    u16* dl = (y == 0) ? ql : (y == 1) ? kl : vl;
    const int i = blockIdx.x * 256 + threadIdx.x;       // 131072 groups of 8
    float xs[8];
    *(float4*)&xs[0] = ((const float4*)src)[i * 2];
    *(float4*)&xs[4] = ((const float4*)src)[i * 2 + 1];
    __align__(16) u16 hb[8];
    __align__(16) u16 lb[8];
    #pragma unroll
    for (int j = 0; j < 8; ++j) {
        const u16 hh = f2bf(xs[j]);
        hb[j] = hh;
        lb[j] = f2bf(xs[j] - bf2f(hh));
    }
    *(uint4*)&dh[i * 8] = *(const uint4*)hb;
    *(uint4*)&dl[i * 8] = *(const uint4*)lb;
}

// single-weight split (for Wo, must run after attn frees its slot)
__global__ __launch_bounds__(256) void split_kernel(
    const float* __restrict__ src, u16* __restrict__ h, u16* __restrict__ l)
{
    const int i = blockIdx.x * 256 + threadIdx.x;
    float xs[8];
    *(float4*)&xs[0] = ((const float4*)src)[i * 2];
    *(float4*)&xs[4] = ((const float4*)src)[i * 2 + 1];
    __align__(16) u16 hb[8];
    __align__(16) u16 lb[8];
    #pragma unroll
    for (int j = 0; j < 8; ++j) {
        const u16 hh = f2bf(xs[j]);
        hb[j] = hh;
        lb[j] = f2bf(xs[j] - bf2f(hh));
    }
    *(uint4*)&h[i * 8] = *(const uint4*)hb;
    *(uint4*)&l[i * 8] = *(const uint4*)lb;
}

// ---------------------------------------------------------------------------
// MFMA split-bf16 GEMM: C = A(Mx1024) @ W^T + bias. BM=128,BN=64,BK=64.
// ABF16=0: A fp32, staged fp32 + split at frag read.
// ABF16=1: A pre-split bf16 hi/lo (attn output path).
// OUT_MODE 0: RoPE(+scale via global tab)+split -> [b][h][s][d] bf16 hi/lo
// OUT_MODE 1: split + TRANSPOSED write -> V^T [b][h][d][s] bf16 hi/lo
// OUT_MODE 2: fp32 row-major Mx1024
// ---------------------------------------------------------------------------
template <int OUT_MODE, int ABF16>
__global__ __launch_bounds__(256) void gemm_mfma_kernel(
    const float* __restrict__ Af,
    const u16* __restrict__ Ah, const u16* __restrict__ Al,
    const u16* __restrict__ Wh, const u16* __restrict__ Wl,
    const float* __restrict__ bias, const float2* __restrict__ tab,
    float rope_scale,
    u16* __restrict__ Oh, u16* __restrict__ Ol, float* __restrict__ Of)
{
    __shared__ uint4 smem4[3072];                 // 48 KB
    u32* smem = (u32*)smem4;
    float* sAf = (float*)smem;                    // [0,8192) u32  (fp32 A)
    u16* sAh = (u16*)smem;                        // [0,4096) u32  (bf16 A hi)
    u16* sAl = (u16*)(smem + 4096);               // [4096,8192)   (bf16 A lo)
    u16* sBh = (u16*)(smem + 8192);               // [8192,10240)
    u16* sBl = (u16*)(smem + 10240);              // [10240,12288)

    const int tid   = threadIdx.x;
    const int w     = tid >> 6;
    const int lane  = tid & 63;
    const int lrow  = lane & 15;
    const int lquad = lane >> 4;
    const int n0    = blockIdx.x * 64;            // = head * 64
    const int m0    = blockIdx.y * 128;

    const int r4   = lane >> 4;                   // A-fp32: row within 4-row slab
    const int s16  = lane & 15;
    const int r8   = lane >> 3;                   // 8-row slab
    const int sch8 = (lane & 7) ^ (r8 & 7);

    // frag offsets
    int aoff[2][2][2];   // fp32 A [ks][mi][half] (float units)
    int aoffb[2][2];     // bf16 A [ks][mi]       (u16 units)
    int boff[2][4];      // B      [ks][ni]       (u16 units)
    #pragma unroll
    for (int ks = 0; ks < 2; ++ks) {
        #pragma unroll
        for (int mi = 0; mi < 2; ++mi) {
            const int ra = w * 32 + mi * 16 + lrow;
            #pragma unroll
            for (int hf = 0; hf < 2; ++hf) {
                const int c = ks * 8 + lquad * 2 + hf;
                aoff[ks][mi][hf] = ra * 64 + ((c ^ (ra & 15)) << 2);
            }
            aoffb[ks][mi] = ra * 64 + (((ks * 4 + lquad) ^ (ra & 7)) << 3);
        }
        #pragma unroll
        for (int ni = 0; ni < 4; ++ni) {
            const int rb = ni * 16 + lrow;
            boff[ks][ni] = rb * 64 + (((ks * 4 + lquad) ^ (rb & 7)) << 3);
        }
    }

    f32x4 acc[2][4] = {};

    for (int k0 = 0; k0 < 1024; k0 += 64) {
        __syncthreads();
        if (ABF16 == 0) {
            #pragma unroll
            for (int i = 0; i < 8; ++i) {
                const int slab = w * 8 + i;
                const int row  = slab * 4 + r4;
                const int gch  = s16 ^ (row & 15);
                gload_lds16f(Af + (size_t)(m0 + row) * 1024 + k0 + gch * 4,
                             sAf + slab * 256);
            }
        } else {
            #pragma unroll
            for (int i = 0; i < 4; ++i) {
                const int slab = w * 4 + i;           // 0..15
                const int row  = slab * 8 + r8;
                gload_lds16(Ah + (size_t)(m0 + row) * 1024 + k0 + sch8 * 8,
                            sAh + slab * 512);
                gload_lds16(Al + (size_t)(m0 + row) * 1024 + k0 + sch8 * 8,
                            sAl + slab * 512);
            }
        }
        #pragma unroll
        for (int i = 0; i < 2; ++i) {
            const int slab = w * 2 + i;               // 0..7
            const int row  = slab * 8 + r8;
            gload_lds16(Wh + (size_t)(n0 + row) * 1024 + k0 + sch8 * 8,
                        sBh + slab * 512);
            gload_lds16(Wl + (size_t)(n0 + row) * 1024 + k0 + sch8 * 8,
                        sBl + slab * 512);
        }
        __syncthreads();

        #pragma unroll
        for (int ks = 0; ks < 2; ++ks) {
            bfrag ah[2], al[2], bh[4], bl[4];
            #pragma unroll
            for (int mi = 0; mi < 2; ++mi) {
                if (ABF16 == 0) {
                    float xf[8];
                    *(float4*)&xf[0] = *(const float4*)&sAf[aoff[ks][mi][0]];
                    *(float4*)&xf[4] = *(const float4*)&sAf[aoff[ks][mi][1]];
                    #pragma unroll
                    for (int j = 0; j < 8; ++j) {
                        const u16 hh = f2bf(xf[j]);
                        ah[mi][j] = (short)hh;
                        al[mi][j] = (short)f2bf(xf[j] - bf2f(hh));
                    }
                } else {
                    ah[mi] = *(const bfrag*)&sAh[aoffb[ks][mi]];
                    al[mi] = *(const bfrag*)&sAl[aoffb[ks][mi]];
                }
            }
            #pragma unroll
            for (int ni = 0; ni < 4; ++ni) {
                bh[ni] = *(const bfrag*)&sBh[boff[ks][ni]];
                bl[ni] = *(const bfrag*)&sBl[boff[ks][ni]];
            }
            #pragma unroll
            for (int mi = 0; mi < 2; ++mi)
                #pragma unroll
                for (int ni = 0; ni < 4; ++ni) {
                    acc[mi][ni] = __builtin_amdgcn_mfma_f32_16x16x32_bf16(ah[mi], bh[ni], acc[mi][ni], 0, 0, 0);
                    acc[mi][ni] = __builtin_amdgcn_mfma_f32_16x16x32_bf16(ah[mi], bl[ni], acc[mi][ni], 0, 0, 0);
                    acc[mi][ni] = __builtin_amdgcn_mfma_f32_16x16x32_bf16(al[mi], bh[ni], acc[mi][ni], 0, 0, 0);
                }
        }
    }

    float bn[4];
    #pragma unroll
    for (int ni = 0; ni < 4; ++ni) bn[ni] = bias[n0 + ni * 16 + lrow];

    if (OUT_MODE == 0) {
        const int hblk = blockIdx.x;
        #pragma unroll
        for (int mi = 0; mi < 2; ++mi)
            #pragma unroll
            for (int r = 0; r < 4; ++r) {
                const int mrow = w * 32 + mi * 16 + lquad * 4 + r;
                const int m  = m0 + mrow;
                const int bb = m & 1;
                const int sg = m >> 1;
                const size_t ob = (((size_t)(bb * NHEADS + hblk) * SEQ) + sg) * HDIM;
                #pragma unroll
                for (int ni = 0; ni < 2; ++ni) {
                    const int i = ni * 16 + lrow;
                    const float2 sc = tab[(size_t)sg * 32 + i];
                    const float x1 = acc[mi][ni][r]     + bn[ni];
                    const float x2 = acc[mi][ni + 2][r] + bn[ni + 2];
                    // reference quirk: o2 = x1*sin - x2*cos
                    const float o1 = (x1 * sc.y - x2 * sc.x) * rope_scale;
                    const float o2 = (x1 * sc.x - x2 * sc.y) * rope_scale;
                    const u16 h1 = f2bf(o1);
                    const u16 h2 = f2bf(o2);
                    Oh[ob + i]      = h1;  Ol[ob + i]      = f2bf(o1 - bf2f(h1));
                    Oh[ob + i + 32] = h2;  Ol[ob + i + 32] = f2bf(o2 - bf2f(h2));
                }
            }
    } else if (OUT_MODE == 1) {
        // split + transpose via LDS: vb[b][d][s_loc], stride 65 breaks banks
        __syncthreads();
        u32* vb = smem;    // 2*64*65 = 8320 u32 <= 12288
        #pragma unroll
        for (int mi = 0; mi < 2; ++mi)
            #pragma unroll
            for (int r = 0; r < 4; ++r) {
                const int mrow = w * 32 + mi * 16 + lquad * 4 + r;
                const int bb = mrow & 1;
                const int sl = mrow >> 1;
                #pragma unroll
                for (int ni = 0; ni < 4; ++ni) {
                    const int d = ni * 16 + lrow;
                    const float v = acc[mi][ni][r] + bn[ni];
                    const u16 hh = f2bf(v);
                    const u16 ll = f2bf(v - bf2f(hh));
                    vb[bb * 4160 + d * 65 + sl] = (u32)hh | ((u32)ll << 16);
                }
            }
        __syncthreads();
        const int hblk = blockIdx.x;
        #pragma unroll
        for (int rep = 0; rep < 4; ++rep) {
            const int c  = rep * 256 + tid;      // 1024 chunks
            const int bb = c >> 9;
            const int d  = (c >> 3) & 63;
            const int s8 = c & 7;
            u32 pk[8];
            #pragma unroll
            for (int j = 0; j < 8; ++j) pk[j] = vb[bb * 4160 + d * 65 + s8 * 8 + j];
            __align__(16) u16 hb[8];
            __align__(16) u16 lb[8];
            #pragma unroll
            for (int j = 0; j < 8; ++j) { hb[j] = (u16)pk[j]; lb[j] = (u16)(pk[j] >> 16); }
            const size_t ob = ((size_t)(bb * NHEADS + hblk) * HDIM + d) * SEQ + (m0 >> 1) + s8 * 8;
            *(uint4*)&Oh[ob] = *(const uint4*)hb;
            *(uint4*)&Ol[ob] = *(const uint4*)lb;
        }
    } else {
        #pragma unroll
        for (int mi = 0; mi < 2; ++mi)
            #pragma unroll
            for (int r = 0; r < 4; ++r) {
                const int m = m0 + w * 32 + mi * 16 + lquad * 4 + r;
                #pragma unroll
                for (int ni = 0; ni < 4; ++ni)
                    Of[(size_t)m * 1024 + n0 + ni * 16 + lrow] = acc[mi][ni][r] + bn[ni];
            }
    }
}

// ---------------------------------------------------------------------------
// MFMA flash attention, 32x32x16, split-bf16, no-max softmax.
// Block = (qt, bh): 4 waves x 32 q-rows = 128-row Q tile; 64-key K-tiles.
// A[m][k]: m=lane&31, k=(lane>>5)*8+j ; B[k][n]: n=lane&31, same k.
// C/D: col=lane&31, row=(reg&3)+8*(reg>>2)+4*(lane>>5).
// P packed (hi|lo<<16) u32 in wave-private LDS, 16B-chunk XOR swizzle.
// Output: split bf16 (S,B,DMODEL) hi/lo for the final ABF16 GEMM.
// ---------------------------------------------------------------------------
__global__ __launch_bounds__(256) void attn_mfma_kernel(
    const u16* __restrict__ Qh, const u16* __restrict__ Ql,
    const u16* __restrict__ Kh, const u16* __restrict__ Kl,
    const u16* __restrict__ Vh, const u16* __restrict__ Vl,
    u16* __restrict__ Oh, u16* __restrict__ Ol)
{
    __shared__ u16 sKh[4096], sKl[4096];   // [key][dh]  swizzled (8KB ea)
    __shared__ u16 sVh[4096], sVl[4096];   // [dh][key]  swizzled
    __shared__ u32 sP[8192];               // 4 waves x 32 q x 64 key packed

    const int tid  = threadIdx.x;
    const int w    = tid >> 6;
    const int lane = tid & 63;
    const int l31  = lane & 31;
    const int g    = lane >> 5;
    const int qt   = blockIdx.x;
    const int bh   = blockIdx.y;

    // Q A-frags (registers), d-offset = ks*16 + g*8
    const size_t qg = ((size_t)bh * SEQ + qt * 128 + w * 32 + l31) * HDIM + g * 8;
    bfrag qfh[4], qfl[4];
    #pragma unroll
    for (int ks = 0; ks < 4; ++ks) {
        qfh[ks] = *(const bfrag*)&Qh[qg + ks * 16];
        qfl[ks] = *(const bfrag*)&Ql[qg + ks * 16];
    }

    // staging: wave w stages one of {sKh,sKl,sVh,sVl}, 8 instrs x 1KB
    const int srow   = lane >> 3;
    const int schunk = (lane & 7) ^ srow;
    const u16* gsrc; u16* lbase; size_t istep, ktstep;
    if (w < 2) {
        gsrc  = ((w == 0) ? Kh : Kl) + ((size_t)bh * SEQ + srow) * HDIM + schunk * 8;
        istep = 8 * 64; ktstep = 64 * 64;
        lbase = (w == 0) ? sKh : sKl;
    } else {
        gsrc  = ((w == 2) ? Vh : Vl) + ((size_t)bh * HDIM + srow) * SEQ + schunk * 8;
        istep = 8 * SEQ; ktstep = 64;
        lbase = (w == 2) ? sVh : sVl;
    }

    // B-frag offsets (u16 units): row = kg*32+l31, chunk = ks*2+g (of 8)
    int koff[2][4];
    #pragma unroll
    for (int kg = 0; kg < 2; ++kg) {
        const int row = kg * 32 + l31;
        #pragma unroll
        for (int ks = 0; ks < 4; ++ks)
            koff[kg][ks] = row * 64 + (((ks * 2 + g) ^ (row & 7)) << 3);
    }
    // P A-frag offsets (u32 units): row = l31, chunks of 4 u32 (16 of them)
    int proff[4][2];
    const int pbase = w * 2048 + l31 * 64;
    #pragma unroll
    for (int kp = 0; kp < 4; ++kp) {
        const int c0 = kp * 4 + g * 2;
        proff[kp][0] = pbase + (((c0    ) ^ (l31 & 15)) << 2);
        proff[kp][1] = pbase + (((c0 + 1) ^ (l31 & 15)) << 2);
    }

    f32x16 accO[2] = {};
    float l_loc[16];
    #pragma unroll
    for (int r = 0; r < 16; ++r) l_loc[r] = 0.0f;

    for (int kt = 0; kt < SEQ / 64; ++kt) {
        __syncthreads();
        const u16* gp = gsrc + (size_t)kt * ktstep;
        #pragma unroll
        for (int i = 0; i < 8; ++i)
            gload_lds16(gp + (size_t)i * istep, lbase + i * 512);
        __syncthreads();

        // ---- S = Q K^T (pre-scaled) ----
        f32x16 accS[2] = {};
        #pragma unroll
        for (int kg = 0; kg < 2; ++kg)
            #pragma unroll
            for (int ks = 0; ks < 4; ++ks) {
                const bfrag kh = *(const bfrag*)&sKh[koff[kg][ks]];
                const bfrag kl = *(const bfrag*)&sKl[koff[kg][ks]];
                accS[kg] = __builtin_amdgcn_mfma_f32_32x32x16_bf16(qfh[ks], kh, accS[kg], 0, 0, 0);
                accS[kg] = __builtin_amdgcn_mfma_f32_32x32x16_bf16(qfl[ks], kh, accS[kg], 0, 0, 0);
                accS[kg] = __builtin_amdgcn_mfma_f32_32x32x16_bf16(qfh[ks], kl, accS[kg], 0, 0, 0);
            }

        // ---- p = exp(s) (no max-sub: softmax-invariant, scores bounded) ----
        #pragma unroll
        for (int kg = 0; kg < 2; ++kg) {
            const int key = kg * 32 + l31;
            const int cb = key >> 2, kc = key & 3;
            #pragma unroll
            for (int r = 0; r < 16; ++r) {
                const int row = (r & 3) + 8 * (r >> 2) + 4 * g;
                const float p = __expf(accS[kg][r]);
                l_loc[r] += p;
                const u16 hh = f2bf(p);
                const u16 ll = f2bf(p - bf2f(hh));
                sP[w * 2048 + row * 64 + ((cb ^ (row & 15)) << 2) + kc] =
                    (u32)hh | ((u32)ll << 16);
            }
        }

        // ---- O += P V (P wave-private; in-wave LDS ordering) ----
        #pragma unroll
        for (int kp = 0; kp < 4; ++kp) {
            const uint4 pa = *(const uint4*)&sP[proff[kp][0]];
            const uint4 pb = *(const uint4*)&sP[proff[kp][1]];
            const u32 pk[8] = {pa.x, pa.y, pa.z, pa.w, pb.x, pb.y, pb.z, pb.w};
            fragu ph, pl;
            #pragma unroll
            for (int j2 = 0; j2 < 4; ++j2) {
                ph.u[j2] = (pk[2 * j2] & 0xffffu) | (pk[2 * j2 + 1] << 16);
                pl.u[j2] = (pk[2 * j2] >> 16) | (pk[2 * j2 + 1] & 0xffff0000u);
            }
            #pragma unroll
            for (int dt = 0; dt < 2; ++dt) {
                const bfrag vh = *(const bfrag*)&sVh[koff[dt][kp]];
                const bfrag vl = *(const bfrag*)&sVl[koff[dt][kp]];
                accO[dt] = __builtin_amdgcn_mfma_f32_32x32x16_bf16(ph.f, vh, accO[dt], 0, 0, 0);
                accO[dt] = __builtin_amdgcn_mfma_f32_32x32x16_bf16(ph.f, vl, accO[dt], 0, 0, 0);
                accO[dt] = __builtin_amdgcn_mfma_f32_32x32x16_bf16(pl.f, vh, accO[dt], 0, 0, 0);
            }
        }
    }

    // ---- one-time l reduction across the 32 columns of each half-wave ----
    #pragma unroll
    for (int r = 0; r < 16; ++r) {
        float s = l_loc[r];
        s += __shfl_xor(s, 1);
        s += __shfl_xor(s, 2);
        s += __shfl_xor(s, 4);
        s += __shfl_xor(s, 8);
        s += __shfl_xor(s, 16);
        l_loc[r] = 1.0f / s;
    }

    const int b = bh >> 4;
    const int h = bh & 15;
    #pragma unroll
    for (int r = 0; r < 16; ++r) {
        const int row = (r & 3) + 8 * (r >> 2) + 4 * g;
        const int sg  = qt * 128 + w * 32 + row;
        #pragma unroll
        for (int dt = 0; dt < 2; ++dt) {
            const float v = accO[dt][r] * l_loc[r];
            const u16 hh = f2bf(v);
            const size_t ob = ((size_t)sg * BATCH + b) * DMODEL + h * 64 + dt * 32 + l31;
            Oh[ob] = hh;
            Ol[ob] = f2bf(v - bf2f(hh));
        }
    }
}

// ---------------------------------------------------------------------------
extern "C" void kernel_launch(void* const* d_in, const int* in_sizes, int n_in,
                              void* d_out, int out_size, void* d_ws, size_t ws_size,
                              hipStream_t stream)
{
    const float* query = (const float*)d_in[0];
    const float* key   = (const float*)d_in[1];
    const float* value = (const float*)d_in[2];
    const float* Wq    = (const float*)d_in[3];
    const float* bq    = (const float*)d_in[4];
    const float* Wk    = (const float*)d_in[5];
    const float* bk    = (const float*)d_in[6];
    const float* Wv    = (const float*)d_in[7];
    const float* bv    = (const float*)d_in[8];
    const float* Wo    = (const float*)d_in[9];
    const float* bo    = (const float*)d_in[10];
    float* out = (float*)d_out;

    // 64 MB workspace, time-multiplexed (MB offsets):
    //  Wq split [0,4), Wk [4,8), Wv [8,12), rope tab [12,12.5)  -- dead after projections
    //  Qh [16,24) Ql [24,32) ; Kh [32,40) Kl [40,48) ; VTh [48,56) VTl [56,64)
    //  attn out split: AOh [0,8) AOl [8,16)   (w-splits + tab dead)
    //  Wo split [16,20)                        (Q dead after attn)
    char* wsb = (char*)d_ws;
    const size_t MB = 1024 * 1024;
    u16* Wqh = (u16*)(wsb + 0 * MB);  u16* Wql = (u16*)(wsb + 2 * MB);
    u16* Wkh = (u16*)(wsb + 4 * MB);  u16* Wkl = (u16*)(wsb + 6 * MB);
    u16* Wvh = (u16*)(wsb + 8 * MB);  u16* Wvl = (u16*)(wsb + 10 * MB);
    float2* tab = (float2*)(wsb + 12 * MB);
    u16* Qh  = (u16*)(wsb + 16 * MB); u16* Ql  = (u16*)(wsb + 24 * MB);
    u16* Kh  = (u16*)(wsb + 32 * MB); u16* Kl  = (u16*)(wsb + 40 * MB);
    u16* VTh = (u16*)(wsb + 48 * MB); u16* VTl = (u16*)(wsb + 56 * MB);
    u16* AOh = (u16*)(wsb + 0 * MB);  u16* AOl = (u16*)(wsb + 8 * MB);
    u16* Woh = (u16*)(wsb + 16 * MB); u16* Wol = (u16*)(wsb + 18 * MB);

    const dim3 ggrid(DMODEL / 64, MROWS / 128);   // (16, 32)

    // weight splits + RoPE table
    prep_kernel<<<dim3(512, 4), 256, 0, stream>>>(Wq, Wk, Wv, Wqh, Wql, Wkh, Wkl, Wvh, Wvl, tab);
    // projections (+RoPE for Q/K; Q pre-scaled by 1/sqrt(64); V writes V^T)
    gemm_mfma_kernel<0, 0><<<ggrid, 256, 0, stream>>>(query, nullptr, nullptr, Wqh, Wql, bq, tab, 0.125f, Qh, Ql, nullptr);
    gemm_mfma_kernel<0, 0><<<ggrid, 256, 0, stream>>>(key, nullptr, nullptr, Wkh, Wkl, bk, tab, 1.0f, Kh, Kl, nullptr);
    gemm_mfma_kernel<1, 0><<<ggrid, 256, 0, stream>>>(value, nullptr, nullptr, Wvh, Wvl, bv, tab, 1.0f, VTh, VTl, nullptr);
    // attention -> split bf16 (S,B,D)
    attn_mfma_kernel<<<dim3(SEQ / 128, BATCH * NHEADS), 256, 0, stream>>>(
        Qh, Ql, Kh, Kl, VTh, VTl, AOh, AOl);
    // output projection (A pre-split bf16)
    split_kernel<<<512, 256, 0, stream>>>(Wo, Woh, Wol);
    gemm_mfma_kernel<2, 1><<<ggrid, 256, 0, stream>>>(nullptr, AOh, AOl, Woh, Wol, bo, tab, 1.0f, nullptr, nullptr, out);
}

// Round 5
// 371.531 us; speedup vs baseline: 3.2252x; 1.0321x over previous
//
#include <hip/hip_runtime.h>

// Problem constants
#define DMODEL 1024
#define NHEADS 16
#define HDIM   64
#define SEQ    2048
#define BATCH  2
#define MROWS  (SEQ*BATCH)   // 4096

typedef unsigned int u32;
typedef unsigned short u16;
typedef __attribute__((ext_vector_type(8))) short bfrag;    // 8 bf16 (A/B frag)
typedef __attribute__((ext_vector_type(4))) float f32x4;    // 16x16 C/D frag
typedef __attribute__((ext_vector_type(16))) float f32x16;  // 32x32 C/D frag
typedef union { u32 u[4]; bfrag f; } fragu;

// bf16 split helpers (RTN-even hi). x ~= hi + lo
__device__ __forceinline__ u32 f2bf(float x) {
    unsigned u = __float_as_uint(x);
    return (u + 0x7fffu + ((u >> 16) & 1u)) >> 16;
}
__device__ __forceinline__ float bf2f(u32 h) {
    return __uint_as_float(h << 16);
}

// async global->LDS, 16B/lane; LDS dest = wave-uniform base (+lane*16 by HW)
__device__ __forceinline__ void gload_lds16(const u16* g, u16* l) {
    __builtin_amdgcn_global_load_lds(
        (const __attribute__((address_space(1))) unsigned int*)g,
        (__attribute__((address_space(3))) unsigned int*)l, 16, 0, 0);
}
__device__ __forceinline__ void gload_lds16f(const float* g, float* l) {
    __builtin_amdgcn_global_load_lds(
        (const __attribute__((address_space(1))) unsigned int*)g,
        (__attribute__((address_space(3))) unsigned int*)l, 16, 0, 0);
}

// ---------------------------------------------------------------------------
// Prep: split Wq/Wk/Wv (y=0..2) + build f64-accurate RoPE table (y=3).
// ---------------------------------------------------------------------------
__global__ __launch_bounds__(256) void prep_kernel(
    const float* __restrict__ Wq, const float* __restrict__ Wk,
    const float* __restrict__ Wv,
    u16* __restrict__ qh, u16* __restrict__ ql,
    u16* __restrict__ kh, u16* __restrict__ kl,
    u16* __restrict__ vh, u16* __restrict__ vl,
    float2* __restrict__ tab)
{
    const int y = blockIdx.y;
    if (y == 3) {
        if (blockIdx.x >= 256) return;
        const int e = blockIdx.x * 256 + threadIdx.x;   // 65536 = 2048 s x 32 i
        const int s = e >> 5, i = e & 31;
        const double th = exp(-(double)i * (9.210340371976184 / 32.0)); // ln(1e4)/32
        double sn, cs;
        sincos((double)s * th, &sn, &cs);
        tab[e] = make_float2((float)sn, (float)cs);
        return;
    }
    const float* src = (y == 0) ? Wq : (y == 1) ? Wk : Wv;
    u16* dh = (y == 0) ? qh : (y == 1) ? kh : vh;
    u16* dl = (y == 0) ? ql : (y == 1) ? kl : vl;
    const int i = blockIdx.x * 256 + threadIdx.x;       // 131072 groups of 8
    float xs[8];
    *(float4*)&xs[0] = ((const float4*)src)[i * 2];
    *(float4*)&xs[4] = ((const float4*)src)[i * 2 + 1];
    __align__(16) u16 hb[8];
    __align__(16) u16 lb[8];
    #pragma unroll
    for (int j = 0; j < 8; ++j) {
        const u32 hh = f2bf(xs[j]);
        hb[j] = (u16)hh;
        lb[j] = (u16)f2bf(xs[j] - bf2f(hh));
    }
    *(uint4*)&dh[i * 8] = *(const uint4*)hb;
    *(uint4*)&dl[i * 8] = *(const uint4*)lb;
}

// single-weight split (for Wo, runs after attn frees its ws slot)
__global__ __launch_bounds__(256) void split_kernel(
    const float* __restrict__ src, u16* __restrict__ h, u16* __restrict__ l)
{
    const int i = blockIdx.x * 256 + threadIdx.x;
    float xs[8];
    *(float4*)&xs[0] = ((const float4*)src)[i * 2];
    *(float4*)&xs[4] = ((const float4*)src)[i * 2 + 1];
    __align__(16) u16 hb[8];
    __align__(16) u16 lb[8];
    #pragma unroll
    for (int j = 0; j < 8; ++j) {
        const u32 hh = f2bf(xs[j]);
        hb[j] = (u16)hh;
        lb[j] = (u16)f2bf(xs[j] - bf2f(hh));
    }
    *(uint4*)&h[i * 8] = *(const uint4*)hb;
    *(uint4*)&l[i * 8] = *(const uint4*)lb;
}

// ---------------------------------------------------------------------------
// MFMA split-bf16 GEMM: C = A(Mx1024) @ W^T + bias. BM=128,BN=64,BK=64.
// XCD-aware remap: linear id%8 ~ XCD; give each XCD 4 consecutive m-tiles x
// all 16 n-tiles so the shared A-tile stays L2-resident (2MB/XCD working set).
// ABF16=0: A fp32, staged fp32 + split at frag read.
// ABF16=1: A pre-split bf16 hi/lo (attn output path).
// OUT_MODE 0: RoPE(+scale via global tab)+split -> [b][h][s][d] bf16 hi/lo
// OUT_MODE 1: split + TRANSPOSED write -> V^T [b][h][d][s] bf16 hi/lo
// OUT_MODE 2: fp32 row-major Mx1024
// ---------------------------------------------------------------------------
template <int OUT_MODE, int ABF16>
__global__ __launch_bounds__(256) void gemm_mfma_kernel(
    const float* __restrict__ Af,
    const u16* __restrict__ Ah, const u16* __restrict__ Al,
    const u16* __restrict__ Wh, const u16* __restrict__ Wl,
    const float* __restrict__ bias, const float2* __restrict__ tab,
    float rope_scale,
    u16* __restrict__ Oh, u16* __restrict__ Ol, float* __restrict__ Of)
{
    __shared__ uint4 smem4[3072];                 // 48 KB
    u32* smem = (u32*)smem4;
    float* sAf = (float*)smem;                    // [0,8192) u32  (fp32 A)
    u16* sAh = (u16*)smem;                        // [0,4096) u32  (bf16 A hi)
    u16* sAl = (u16*)(smem + 4096);               // [4096,8192)   (bf16 A lo)
    u16* sBh = (u16*)(smem + 8192);               // [8192,10240)
    u16* sBl = (u16*)(smem + 10240);              // [10240,12288)

    const int tid   = threadIdx.x;
    const int w     = tid >> 6;
    const int lane  = tid & 63;
    const int lrow  = lane & 15;
    const int lquad = lane >> 4;

    // XCD-aware remap (id%8 ~ XCD on MI355X; perf heuristic only)
    const int id   = blockIdx.x + 16 * blockIdx.y;   // 0..511
    const int xcd  = id & 7;
    const int jj   = id >> 3;                        // 0..63
    const int nblk = jj & 15;
    const int mblk = (xcd << 2) | (jj >> 4);
    const int n0   = nblk * 64;                      // = head * 64
    const int m0   = mblk * 128;

    const int r4   = lane >> 4;                   // A-fp32: row within 4-row slab
    const int s16  = lane & 15;
    const int r8   = lane >> 3;                   // 8-row slab
    const int sch8 = (lane & 7) ^ (r8 & 7);

    // frag offsets
    int aoff[2][2][2];   // fp32 A [ks][mi][half] (float units)
    int aoffb[2][2];     // bf16 A [ks][mi]       (u16 units)
    int boff[2][4];      // B      [ks][ni]       (u16 units)
    #pragma unroll
    for (int ks = 0; ks < 2; ++ks) {
        #pragma unroll
        for (int mi = 0; mi < 2; ++mi) {
            const int ra = w * 32 + mi * 16 + lrow;
            #pragma unroll
            for (int hf = 0; hf < 2; ++hf) {
                const int c = ks * 8 + lquad * 2 + hf;
                aoff[ks][mi][hf] = ra * 64 + ((c ^ (ra & 15)) << 2);
            }
            aoffb[ks][mi] = ra * 64 + (((ks * 4 + lquad) ^ (ra & 7)) << 3);
        }
        #pragma unroll
        for (int ni = 0; ni < 4; ++ni) {
            const int rb = ni * 16 + lrow;
            boff[ks][ni] = rb * 64 + (((ks * 4 + lquad) ^ (rb & 7)) << 3);
        }
    }

    f32x4 acc[2][4] = {};

    for (int k0 = 0; k0 < 1024; k0 += 64) {
        __syncthreads();
        if (ABF16 == 0) {
            #pragma unroll
            for (int i = 0; i < 8; ++i) {
                const int slab = w * 8 + i;
                const int row  = slab * 4 + r4;
                const int gch  = s16 ^ (row & 15);
                gload_lds16f(Af + (size_t)(m0 + row) * 1024 + k0 + gch * 4,
                             sAf + slab * 256);
            }
        } else {
            #pragma unroll
            for (int i = 0; i < 4; ++i) {
                const int slab = w * 4 + i;           // 0..15
                const int row  = slab * 8 + r8;
                gload_lds16(Ah + (size_t)(m0 + row) * 1024 + k0 + sch8 * 8,
                            sAh + slab * 512);
                gload_lds16(Al + (size_t)(m0 + row) * 1024 + k0 + sch8 * 8,
                            sAl + slab * 512);
            }
        }
        #pragma unroll
        for (int i = 0; i < 2; ++i) {
            const int slab = w * 2 + i;               // 0..7
            const int row  = slab * 8 + r8;
            gload_lds16(Wh + (size_t)(n0 + row) * 1024 + k0 + sch8 * 8,
                        sBh + slab * 512);
            gload_lds16(Wl + (size_t)(n0 + row) * 1024 + k0 + sch8 * 8,
                        sBl + slab * 512);
        }
        __syncthreads();

        #pragma unroll
        for (int ks = 0; ks < 2; ++ks) {
            bfrag ah[2], al[2], bh[4], bl[4];
            #pragma unroll
            for (int mi = 0; mi < 2; ++mi) {
                if (ABF16 == 0) {
                    float xf[8];
                    *(float4*)&xf[0] = *(const float4*)&sAf[aoff[ks][mi][0]];
                    *(float4*)&xf[4] = *(const float4*)&sAf[aoff[ks][mi][1]];
                    #pragma unroll
                    for (int j = 0; j < 8; ++j) {
                        const u32 hh = f2bf(xf[j]);
                        ah[mi][j] = (short)hh;
                        al[mi][j] = (short)f2bf(xf[j] - bf2f(hh));
                    }
                } else {
                    ah[mi] = *(const bfrag*)&sAh[aoffb[ks][mi]];
                    al[mi] = *(const bfrag*)&sAl[aoffb[ks][mi]];
                }
            }
            #pragma unroll
            for (int ni = 0; ni < 4; ++ni) {
                bh[ni] = *(const bfrag*)&sBh[boff[ks][ni]];
                bl[ni] = *(const bfrag*)&sBl[boff[ks][ni]];
            }
            #pragma unroll
            for (int mi = 0; mi < 2; ++mi)
                #pragma unroll
                for (int ni = 0; ni < 4; ++ni) {
                    acc[mi][ni] = __builtin_amdgcn_mfma_f32_16x16x32_bf16(ah[mi], bh[ni], acc[mi][ni], 0, 0, 0);
                    acc[mi][ni] = __builtin_amdgcn_mfma_f32_16x16x32_bf16(ah[mi], bl[ni], acc[mi][ni], 0, 0, 0);
                    acc[mi][ni] = __builtin_amdgcn_mfma_f32_16x16x32_bf16(al[mi], bh[ni], acc[mi][ni], 0, 0, 0);
                }
        }
    }

    float bn[4];
    #pragma unroll
    for (int ni = 0; ni < 4; ++ni) bn[ni] = bias[n0 + ni * 16 + lrow];

    if (OUT_MODE == 0) {
        const int hblk = nblk;
        #pragma unroll
        for (int mi = 0; mi < 2; ++mi)
            #pragma unroll
            for (int r = 0; r < 4; ++r) {
                const int mrow = w * 32 + mi * 16 + lquad * 4 + r;
                const int m  = m0 + mrow;
                const int bb = m & 1;
                const int sg = m >> 1;
                const size_t ob = (((size_t)(bb * NHEADS + hblk) * SEQ) + sg) * HDIM;
                #pragma unroll
                for (int ni = 0; ni < 2; ++ni) {
                    const int i = ni * 16 + lrow;
                    const float2 sc = tab[(size_t)sg * 32 + i];
                    const float x1 = acc[mi][ni][r]     + bn[ni];
                    const float x2 = acc[mi][ni + 2][r] + bn[ni + 2];
                    // reference quirk: o2 = x1*sin - x2*cos
                    const float o1 = (x1 * sc.y - x2 * sc.x) * rope_scale;
                    const float o2 = (x1 * sc.x - x2 * sc.y) * rope_scale;
                    const u32 h1 = f2bf(o1);
                    const u32 h2 = f2bf(o2);
                    Oh[ob + i]      = (u16)h1;  Ol[ob + i]      = (u16)f2bf(o1 - bf2f(h1));
                    Oh[ob + i + 32] = (u16)h2;  Ol[ob + i + 32] = (u16)f2bf(o2 - bf2f(h2));
                }
            }
    } else if (OUT_MODE == 1) {
        // split + transpose via LDS: vb[b][d][s_loc], stride 65 breaks banks
        __syncthreads();
        u32* vb = smem;    // 2*64*65 = 8320 u32 <= 12288
        #pragma unroll
        for (int mi = 0; mi < 2; ++mi)
            #pragma unroll
            for (int r = 0; r < 4; ++r) {
                const int mrow = w * 32 + mi * 16 + lquad * 4 + r;
                const int bb = mrow & 1;
                const int sl = mrow >> 1;
                #pragma unroll
                for (int ni = 0; ni < 4; ++ni) {
                    const int d = ni * 16 + lrow;
                    const float v = acc[mi][ni][r] + bn[ni];
                    const u32 hh = f2bf(v);
                    const u32 ll = f2bf(v - bf2f(hh));
                    vb[bb * 4160 + d * 65 + sl] = hh | (ll << 16);
                }
            }
        __syncthreads();
        const int hblk = nblk;
        #pragma unroll
        for (int rep = 0; rep < 4; ++rep) {
            const int c  = rep * 256 + tid;      // 1024 chunks
            const int bb = c >> 9;
            const int d  = (c >> 3) & 63;
            const int s8 = c & 7;
            u32 pk[8];
            #pragma unroll
            for (int j = 0; j < 8; ++j) pk[j] = vb[bb * 4160 + d * 65 + s8 * 8 + j];
            __align__(16) u16 hb[8];
            __align__(16) u16 lb[8];
            #pragma unroll
            for (int j = 0; j < 8; ++j) { hb[j] = (u16)pk[j]; lb[j] = (u16)(pk[j] >> 16); }
            const size_t ob = ((size_t)(bb * NHEADS + hblk) * HDIM + d) * SEQ + (m0 >> 1) + s8 * 8;
            *(uint4*)&Oh[ob] = *(const uint4*)hb;
            *(uint4*)&Ol[ob] = *(const uint4*)lb;
        }
    } else {
        #pragma unroll
        for (int mi = 0; mi < 2; ++mi)
            #pragma unroll
            for (int r = 0; r < 4; ++r) {
                const int m = m0 + w * 32 + mi * 16 + lquad * 4 + r;
                #pragma unroll
                for (int ni = 0; ni < 4; ++ni)
                    Of[(size_t)m * 1024 + n0 + ni * 16 + lrow] = acc[mi][ni][r] + bn[ni];
            }
    }
}

// ---------------------------------------------------------------------------
// MFMA flash attention, 32x32x16, split-bf16, no-max softmax, S^T/O^T form.
// Block = 128 threads (2 waves) = 64 q-rows; grid (32 qt, 32 bh), 4 blk/CU.
// S^T = K Q^T: A=K frag (rows=keys), B=Q frag (cols=q, in registers).
//   C: lane=q-col, regs=keys -> P stays in REGISTERS (no LDS round-trip).
// P^T B-frags assembled from exp(S^T) regs via __shfl_xor(.,32) g-exchange.
// O^T = V^T P^T: A=V^T frag (rows=d), C: lane=q, regs=d.
// LDS = 32 KB (K/V hi/lo tiles only), XOR chunk-swizzled, conflict-free.
// ---------------------------------------------------------------------------
__global__ __launch_bounds__(128) void attn_mfma_kernel(
    const u16* __restrict__ Qh, const u16* __restrict__ Ql,
    const u16* __restrict__ Kh, const u16* __restrict__ Kl,
    const u16* __restrict__ Vh, const u16* __restrict__ Vl,
    u16* __restrict__ Oh, u16* __restrict__ Ol)
{
    __shared__ u16 sKh[4096], sKl[4096];   // [key][dh]  swizzled (8KB ea)
    __shared__ u16 sVh[4096], sVl[4096];   // [dh][key]  swizzled

    const int tid  = threadIdx.x;
    const int w    = tid >> 6;             // 0..1
    const int lane = tid & 63;
    const int l31  = lane & 31;
    const int g    = lane >> 5;

    // XCD-aware remap: 4 bh per XCD so K/V tiles are L2-local
    const int id = blockIdx.x + 32 * blockIdx.y;   // 0..1023
    const int jj = id >> 3;                        // 0..127
    const int bh = ((id & 7) << 2) | (jj >> 5);
    const int qt = jj & 31;

    // Q B-frags (registers): col=q=l31, k = ks*16 + g*8 + j
    const size_t qg = ((size_t)bh * SEQ + qt * 64 + w * 32 + l31) * HDIM + g * 8;
    bfrag qfh[4], qfl[4];
    #pragma unroll
    for (int ks = 0; ks < 4; ++ks) {
        qfh[ks] = *(const bfrag*)&Qh[qg + ks * 16];
        qfl[ks] = *(const bfrag*)&Ql[qg + ks * 16];
    }

    // staging: wave 0 -> sKh,sKl ; wave 1 -> sVh,sVl (16 gloads each)
    const int srow   = lane >> 3;
    const int schunk = (lane & 7) ^ srow;
    const u16* gsrc0; const u16* gsrc1; u16* lb0; u16* lb1;
    size_t istep, ktstep;
    if (w == 0) {
        gsrc0 = Kh + ((size_t)bh * SEQ + srow) * HDIM + schunk * 8;
        gsrc1 = Kl + ((size_t)bh * SEQ + srow) * HDIM + schunk * 8;
        istep = 8 * 64; ktstep = 64 * 64;
        lb0 = sKh; lb1 = sKl;
    } else {
        gsrc0 = Vh + ((size_t)bh * HDIM + srow) * SEQ + schunk * 8;
        gsrc1 = Vl + ((size_t)bh * HDIM + srow) * SEQ + schunk * 8;
        istep = 8 * SEQ; ktstep = 64;
        lb0 = sVh; lb1 = sVl;
    }

    // frag offsets (u16 units): row-block a (32 rows), 16B chunk c of 8
    int koff[2][4];
    #pragma unroll
    for (int a = 0; a < 2; ++a) {
        const int row = a * 32 + l31;
        #pragma unroll
        for (int c = 0; c < 4; ++c)
            koff[a][c] = row * 64 + (((c * 2 + g) ^ (row & 7)) << 3);
    }

    f32x16 accO[2] = {};
    float l_loc = 0.0f;

    for (int kt = 0; kt < SEQ / 64; ++kt) {
        __syncthreads();
        const u16* g0 = gsrc0 + (size_t)kt * ktstep;
        const u16* g1 = gsrc1 + (size_t)kt * ktstep;
        #pragma unroll
        for (int i = 0; i < 8; ++i) {
            gload_lds16(g0 + (size_t)i * istep, lb0 + i * 512);
            gload_lds16(g1 + (size_t)i * istep, lb1 + i * 512);
        }
        __syncthreads();

        // ---- S^T = K Q^T (Q pre-scaled) : lane=q, regs=keys ----
        f32x16 accS[2] = {};
        #pragma unroll
        for (int kg = 0; kg < 2; ++kg)
            #pragma unroll
            for (int ks = 0; ks < 4; ++ks) {
                const bfrag kh = *(const bfrag*)&sKh[koff[kg][ks]];
                const bfrag kl = *(const bfrag*)&sKl[koff[kg][ks]];
                accS[kg] = __builtin_amdgcn_mfma_f32_32x32x16_bf16(kh, qfh[ks], accS[kg], 0, 0, 0);
                accS[kg] = __builtin_amdgcn_mfma_f32_32x32x16_bf16(kh, qfl[ks], accS[kg], 0, 0, 0);
                accS[kg] = __builtin_amdgcn_mfma_f32_32x32x16_bf16(kl, qfh[ks], accS[kg], 0, 0, 0);
            }

        // ---- p = exp(s): stays in registers (lane=q, reg=key) ----
        float pv[2][16];
        #pragma unroll
        for (int kg = 0; kg < 2; ++kg)
            #pragma unroll
            for (int r = 0; r < 16; ++r) {
                const float p = __expf(accS[kg][r]);
                pv[kg][r] = p;
                l_loc += p;
            }

        // ---- O^T += V^T P^T, P^T B-frags via g-half exchange ----
        #pragma unroll
        for (int kp = 0; kp < 4; ++kp) {
            const int kg = kp >> 1;
            const int c  = (kp & 1) * 8;
            float lo4[4], hi4[4];
            #pragma unroll
            for (int i = 0; i < 4; ++i) {
                const float a = pv[kg][c + i];        // keys j'=0..3 (held by g=0)
                const float b = pv[kg][c + 4 + i];    // keys j'=4..7 (held by g=1)
                const float own  = g ? b : a;
                const float send = g ? a : b;
                const float recv = __shfl_xor(send, 32);
                lo4[i] = g ? recv : own;
                hi4[i] = g ? own : recv;
            }
            fragu ph, pl;
            #pragma unroll
            for (int pr = 0; pr < 2; ++pr) {
                const u32 h0 = f2bf(lo4[2 * pr]);
                const u32 h1 = f2bf(lo4[2 * pr + 1]);
                ph.u[pr] = h0 | (h1 << 16);
                const u32 d0 = __float_as_uint(lo4[2 * pr]     - bf2f(h0));
                const u32 d1 = __float_as_uint(lo4[2 * pr + 1] - bf2f(h1));
                pl.u[pr] = (d0 >> 16) | (d1 & 0xffff0000u);
                const u32 h2 = f2bf(hi4[2 * pr]);
                const u32 h3 = f2bf(hi4[2 * pr + 1]);
                ph.u[2 + pr] = h2 | (h3 << 16);
                const u32 d2 = __float_as_uint(hi4[2 * pr]     - bf2f(h2));
                const u32 d3 = __float_as_uint(hi4[2 * pr + 1] - bf2f(h3));
                pl.u[2 + pr] = (d2 >> 16) | (d3 & 0xffff0000u);
            }
            #pragma unroll
            for (int dt = 0; dt < 2; ++dt) {
                const bfrag vh = *(const bfrag*)&sVh[koff[dt][kp]];
                const bfrag vl = *(const bfrag*)&sVl[koff[dt][kp]];
                accO[dt] = __builtin_amdgcn_mfma_f32_32x32x16_bf16(vh, ph.f, accO[dt], 0, 0, 0);
                accO[dt] = __builtin_amdgcn_mfma_f32_32x32x16_bf16(vh, pl.f, accO[dt], 0, 0, 0);
                accO[dt] = __builtin_amdgcn_mfma_f32_32x32x16_bf16(vl, ph.f, accO[dt], 0, 0, 0);
            }
        }
    }

    // ---- l: combine the two complementary g-halves, then write O ----
    const float inv = 1.0f / (l_loc + __shfl_xor(l_loc, 32));

    const int b = bh >> 4;
    const int h = bh & 15;
    const int sg = qt * 64 + w * 32 + l31;
    const size_t obase = ((size_t)sg * BATCH + b) * DMODEL + h * 64;
    #pragma unroll
    for (int dt = 0; dt < 2; ++dt)
        #pragma unroll
        for (int rq = 0; rq < 4; ++rq) {
            const int d0 = 8 * rq + 4 * g + 32 * dt;
            u32 hw[2], lw[2];
            #pragma unroll
            for (int pr = 0; pr < 2; ++pr) {
                const float v0 = accO[dt][rq * 4 + 2 * pr]     * inv;
                const float v1 = accO[dt][rq * 4 + 2 * pr + 1] * inv;
                const u32 h0 = f2bf(v0);
                const u32 h1 = f2bf(v1);
                hw[pr] = h0 | (h1 << 16);
                const u32 e0 = __float_as_uint(v0 - bf2f(h0));
                const u32 e1 = __float_as_uint(v1 - bf2f(h1));
                lw[pr] = (e0 >> 16) | (e1 & 0xffff0000u);
            }
            *(uint2*)&Oh[obase + d0] = make_uint2(hw[0], hw[1]);
            *(uint2*)&Ol[obase + d0] = make_uint2(lw[0], lw[1]);
        }
}

// ---------------------------------------------------------------------------
extern "C" void kernel_launch(void* const* d_in, const int* in_sizes, int n_in,
                              void* d_out, int out_size, void* d_ws, size_t ws_size,
                              hipStream_t stream)
{
    const float* query = (const float*)d_in[0];
    const float* key   = (const float*)d_in[1];
    const float* value = (const float*)d_in[2];
    const float* Wq    = (const float*)d_in[3];
    const float* bq    = (const float*)d_in[4];
    const float* Wk    = (const float*)d_in[5];
    const float* bk    = (const float*)d_in[6];
    const float* Wv    = (const float*)d_in[7];
    const float* bv    = (const float*)d_in[8];
    const float* Wo    = (const float*)d_in[9];
    const float* bo    = (const float*)d_in[10];
    float* out = (float*)d_out;

    // 64 MB workspace, time-multiplexed (MB offsets):
    //  Wq split [0,4), Wk [4,8), Wv [8,12), rope tab [12,12.5)  -- dead after projections
    //  Qh [16,24) Ql [24,32) ; Kh [32,40) Kl [40,48) ; VTh [48,56) VTl [56,64)
    //  attn out split: AOh [0,8) AOl [8,16)   (w-splits + tab dead)
    //  Wo split [16,20)                        (Q dead after attn)
    char* wsb = (char*)d_ws;
    const size_t MB = 1024 * 1024;
    u16* Wqh = (u16*)(wsb + 0 * MB);  u16* Wql = (u16*)(wsb + 2 * MB);
    u16* Wkh = (u16*)(wsb + 4 * MB);  u16* Wkl = (u16*)(wsb + 6 * MB);
    u16* Wvh = (u16*)(wsb + 8 * MB);  u16* Wvl = (u16*)(wsb + 10 * MB);
    float2* tab = (float2*)(wsb + 12 * MB);
    u16* Qh  = (u16*)(wsb + 16 * MB); u16* Ql  = (u16*)(wsb + 24 * MB);
    u16* Kh  = (u16*)(wsb + 32 * MB); u16* Kl  = (u16*)(wsb + 40 * MB);
    u16* VTh = (u16*)(wsb + 48 * MB); u16* VTl = (u16*)(wsb + 56 * MB);
    u16* AOh = (u16*)(wsb + 0 * MB);  u16* AOl = (u16*)(wsb + 8 * MB);
    u16* Woh = (u16*)(wsb + 16 * MB); u16* Wol = (u16*)(wsb + 18 * MB);

    const dim3 ggrid(DMODEL / 64, MROWS / 128);   // (16, 32)

    // weight splits + RoPE table
    prep_kernel<<<dim3(512, 4), 256, 0, stream>>>(Wq, Wk, Wv, Wqh, Wql, Wkh, Wkl, Wvh, Wvl, tab);
    // projections (+RoPE for Q/K; Q pre-scaled by 1/sqrt(64); V writes V^T)
    gemm_mfma_kernel<0, 0><<<ggrid, 256, 0, stream>>>(query, nullptr, nullptr, Wqh, Wql, bq, tab, 0.125f, Qh, Ql, nullptr);
    gemm_mfma_kernel<0, 0><<<ggrid, 256, 0, stream>>>(key, nullptr, nullptr, Wkh, Wkl, bk, tab, 1.0f, Kh, Kl, nullptr);
    gemm_mfma_kernel<1, 0><<<ggrid, 256, 0, stream>>>(value, nullptr, nullptr, Wvh, Wvl, bv, tab, 1.0f, VTh, VTl, nullptr);
    // attention -> split bf16 (S,B,D)
    attn_mfma_kernel<<<dim3(SEQ / 64, BATCH * NHEADS), 128, 0, stream>>>(
        Qh, Ql, Kh, Kl, VTh, VTl, AOh, AOl);
    // output projection (A pre-split bf16)
    split_kernel<<<512, 256, 0, stream>>>(Wo, Woh, Wol);
    gemm_mfma_kernel<2, 1><<<ggrid, 256, 0, stream>>>(nullptr, AOh, AOl, Woh, Wol, bo, tab, 1.0f, nullptr, nullptr, out);
}

// Round 6
// 358.276 us; speedup vs baseline: 3.3445x; 1.0370x over previous
//
#include <hip/hip_runtime.h>

// Problem constants
#define DMODEL 1024
#define NHEADS 16
#define HDIM   64
#define SEQ    2048
#define BATCH  2
#define MROWS  (SEQ*BATCH)   // 4096

typedef unsigned int u32;
typedef unsigned short u16;
typedef __attribute__((ext_vector_type(8))) short bfrag;    // 8 bf16 (A/B frag)
typedef __attribute__((ext_vector_type(4))) float f32x4;    // 16x16 C/D frag
typedef __attribute__((ext_vector_type(16))) float f32x16;  // 32x32 C/D frag
typedef union { u32 u[4]; bfrag f; } fragu;

// bf16 split helpers (RTN-even hi). x ~= hi + lo
__device__ __forceinline__ u32 f2bf(float x) {
    unsigned u = __float_as_uint(x);
    return (u + 0x7fffu + ((u >> 16) & 1u)) >> 16;
}
__device__ __forceinline__ float bf2f(u32 h) {
    return __uint_as_float(h << 16);
}

// async global->LDS, 16B/lane; LDS dest = wave-uniform base (+lane*16 by HW)
__device__ __forceinline__ void gload_lds16(const u16* g, u16* l) {
    __builtin_amdgcn_global_load_lds(
        (const __attribute__((address_space(1))) unsigned int*)g,
        (__attribute__((address_space(3))) unsigned int*)l, 16, 0, 0);
}
__device__ __forceinline__ void gload_lds16f(const float* g, float* l) {
    __builtin_amdgcn_global_load_lds(
        (const __attribute__((address_space(1))) unsigned int*)g,
        (__attribute__((address_space(3))) unsigned int*)l, 16, 0, 0);
}

// ---------------------------------------------------------------------------
// Prep: split Wq/Wk/Wv (y=0..2) + build f64-accurate RoPE table (y=3).
// ---------------------------------------------------------------------------
__global__ __launch_bounds__(256) void prep_kernel(
    const float* __restrict__ Wq, const float* __restrict__ Wk,
    const float* __restrict__ Wv,
    u16* __restrict__ qh, u16* __restrict__ ql,
    u16* __restrict__ kh, u16* __restrict__ kl,
    u16* __restrict__ vh, u16* __restrict__ vl,
    float2* __restrict__ tab)
{
    const int y = blockIdx.y;
    if (y == 3) {
        if (blockIdx.x >= 256) return;
        const int e = blockIdx.x * 256 + threadIdx.x;   // 65536 = 2048 s x 32 i
        const int s = e >> 5, i = e & 31;
        const double th = exp(-(double)i * (9.210340371976184 / 32.0)); // ln(1e4)/32
        double sn, cs;
        sincos((double)s * th, &sn, &cs);
        tab[e] = make_float2((float)sn, (float)cs);
        return;
    }
    const float* src = (y == 0) ? Wq : (y == 1) ? Wk : Wv;
    u16* dh = (y == 0) ? qh : (y == 1) ? kh : vh;
    u16* dl = (y == 0) ? ql : (y == 1) ? kl : vl;
    const int i = blockIdx.x * 256 + threadIdx.x;       // 131072 groups of 8
    float xs[8];
    *(float4*)&xs[0] = ((const float4*)src)[i * 2];
    *(float4*)&xs[4] = ((const float4*)src)[i * 2 + 1];
    __align__(16) u16 hb[8];
    __align__(16) u16 lb[8];
    #pragma unroll
    for (int j = 0; j < 8; ++j) {
        const u32 hh = f2bf(xs[j]);
        hb[j] = (u16)hh;
        lb[j] = (u16)f2bf(xs[j] - bf2f(hh));
    }
    *(uint4*)&dh[i * 8] = *(const uint4*)hb;
    *(uint4*)&dl[i * 8] = *(const uint4*)lb;
}

// single-weight split (for Wo, runs after attn frees its ws slot)
__global__ __launch_bounds__(256) void split_kernel(
    const float* __restrict__ src, u16* __restrict__ h, u16* __restrict__ l)
{
    const int i = blockIdx.x * 256 + threadIdx.x;
    float xs[8];
    *(float4*)&xs[0] = ((const float4*)src)[i * 2];
    *(float4*)&xs[4] = ((const float4*)src)[i * 2 + 1];
    __align__(16) u16 hb[8];
    __align__(16) u16 lb[8];
    #pragma unroll
    for (int j = 0; j < 8; ++j) {
        const u32 hh = f2bf(xs[j]);
        hb[j] = (u16)hh;
        lb[j] = (u16)f2bf(xs[j] - bf2f(hh));
    }
    *(uint4*)&h[i * 8] = *(const uint4*)hb;
    *(uint4*)&l[i * 8] = *(const uint4*)lb;
}

// ---------------------------------------------------------------------------
// Core split-bf16 MFMA GEMM body, shared by the merged QKV kernel and the
// final projection. C = A(Mx1024) @ W^T + bias. BM=128,BN=64,BK=64.
// XCD-aware remap: id%8 ~ XCD; each XCD gets 4 consecutive m-tiles x 16 n.
// mode 0: RoPE(+scale via tab)+split -> [b][h][s][d] bf16 hi/lo (Q/K)
// mode 1: split + transposed write   -> V^T [b][h][d][s] bf16 hi/lo
// mode 2: fp32 row-major Mx1024 (final output)
// ---------------------------------------------------------------------------
template <int ABF16>
__device__ __forceinline__ void gemm_body(
    int id, int mode,
    const float* __restrict__ Af,
    const u16* __restrict__ Ah, const u16* __restrict__ Al,
    const u16* __restrict__ Wh, const u16* __restrict__ Wl,
    const float* __restrict__ bias, const float2* __restrict__ tab,
    float rope_scale,
    u16* __restrict__ Oh, u16* __restrict__ Ol, float* __restrict__ Of,
    u32* smem)
{
    float* sAf = (float*)smem;                    // [0,8192) u32  (fp32 A)
    u16* sAh = (u16*)smem;                        // [0,4096) u32  (bf16 A hi)
    u16* sAl = (u16*)(smem + 4096);               // [4096,8192)   (bf16 A lo)
    u16* sBh = (u16*)(smem + 8192);               // [8192,10240)
    u16* sBl = (u16*)(smem + 10240);              // [10240,12288)

    const int tid   = threadIdx.x;
    const int w     = tid >> 6;
    const int lane  = tid & 63;
    const int lrow  = lane & 15;
    const int lquad = lane >> 4;

    // XCD-aware remap (id%8 ~ XCD on MI355X; perf heuristic only)
    const int xcd  = id & 7;
    const int jj   = id >> 3;                        // 0..63
    const int nblk = jj & 15;
    const int mblk = (xcd << 2) | (jj >> 4);
    const int n0   = nblk * 64;                      // = head * 64
    const int m0   = mblk * 128;

    const int r4   = lane >> 4;                   // A-fp32: row within 4-row slab
    const int s16  = lane & 15;
    const int r8   = lane >> 3;                   // 8-row slab
    const int sch8 = (lane & 7) ^ (r8 & 7);

    // frag offsets
    int aoff[2][2][2];   // fp32 A [ks][mi][half] (float units)
    int aoffb[2][2];     // bf16 A [ks][mi]       (u16 units)
    int boff[2][4];      // B      [ks][ni]       (u16 units)
    #pragma unroll
    for (int ks = 0; ks < 2; ++ks) {
        #pragma unroll
        for (int mi = 0; mi < 2; ++mi) {
            const int ra = w * 32 + mi * 16 + lrow;
            #pragma unroll
            for (int hf = 0; hf < 2; ++hf) {
                const int c = ks * 8 + lquad * 2 + hf;
                aoff[ks][mi][hf] = ra * 64 + ((c ^ (ra & 15)) << 2);
            }
            aoffb[ks][mi] = ra * 64 + (((ks * 4 + lquad) ^ (ra & 7)) << 3);
        }
        #pragma unroll
        for (int ni = 0; ni < 4; ++ni) {
            const int rb = ni * 16 + lrow;
            boff[ks][ni] = rb * 64 + (((ks * 4 + lquad) ^ (rb & 7)) << 3);
        }
    }

    f32x4 acc[2][4] = {};

    for (int k0 = 0; k0 < 1024; k0 += 64) {
        __syncthreads();
        if (ABF16 == 0) {
            #pragma unroll
            for (int i = 0; i < 8; ++i) {
                const int slab = w * 8 + i;
                const int row  = slab * 4 + r4;
                const int gch  = s16 ^ (row & 15);
                gload_lds16f(Af + (size_t)(m0 + row) * 1024 + k0 + gch * 4,
                             sAf + slab * 256);
            }
        } else {
            #pragma unroll
            for (int i = 0; i < 4; ++i) {
                const int slab = w * 4 + i;           // 0..15
                const int row  = slab * 8 + r8;
                gload_lds16(Ah + (size_t)(m0 + row) * 1024 + k0 + sch8 * 8,
                            sAh + slab * 512);
                gload_lds16(Al + (size_t)(m0 + row) * 1024 + k0 + sch8 * 8,
                            sAl + slab * 512);
            }
        }
        #pragma unroll
        for (int i = 0; i < 2; ++i) {
            const int slab = w * 2 + i;               // 0..7
            const int row  = slab * 8 + r8;
            gload_lds16(Wh + (size_t)(n0 + row) * 1024 + k0 + sch8 * 8,
                        sBh + slab * 512);
            gload_lds16(Wl + (size_t)(n0 + row) * 1024 + k0 + sch8 * 8,
                        sBl + slab * 512);
        }
        __syncthreads();

        #pragma unroll
        for (int ks = 0; ks < 2; ++ks) {
            bfrag ah[2], al[2], bh[4], bl[4];
            #pragma unroll
            for (int mi = 0; mi < 2; ++mi) {
                if (ABF16 == 0) {
                    float xf[8];
                    *(float4*)&xf[0] = *(const float4*)&sAf[aoff[ks][mi][0]];
                    *(float4*)&xf[4] = *(const float4*)&sAf[aoff[ks][mi][1]];
                    #pragma unroll
                    for (int j = 0; j < 8; ++j) {
                        const u32 hh = f2bf(xf[j]);
                        ah[mi][j] = (short)hh;
                        al[mi][j] = (short)f2bf(xf[j] - bf2f(hh));
                    }
                } else {
                    ah[mi] = *(const bfrag*)&sAh[aoffb[ks][mi]];
                    al[mi] = *(const bfrag*)&sAl[aoffb[ks][mi]];
                }
            }
            #pragma unroll
            for (int ni = 0; ni < 4; ++ni) {
                bh[ni] = *(const bfrag*)&sBh[boff[ks][ni]];
                bl[ni] = *(const bfrag*)&sBl[boff[ks][ni]];
            }
            #pragma unroll
            for (int mi = 0; mi < 2; ++mi)
                #pragma unroll
                for (int ni = 0; ni < 4; ++ni) {
                    acc[mi][ni] = __builtin_amdgcn_mfma_f32_16x16x32_bf16(ah[mi], bh[ni], acc[mi][ni], 0, 0, 0);
                    acc[mi][ni] = __builtin_amdgcn_mfma_f32_16x16x32_bf16(ah[mi], bl[ni], acc[mi][ni], 0, 0, 0);
                    acc[mi][ni] = __builtin_amdgcn_mfma_f32_16x16x32_bf16(al[mi], bh[ni], acc[mi][ni], 0, 0, 0);
                }
        }
    }

    float bn[4];
    #pragma unroll
    for (int ni = 0; ni < 4; ++ni) bn[ni] = bias[n0 + ni * 16 + lrow];

    if (mode == 0) {
        const int hblk = nblk;
        #pragma unroll
        for (int mi = 0; mi < 2; ++mi)
            #pragma unroll
            for (int r = 0; r < 4; ++r) {
                const int mrow = w * 32 + mi * 16 + lquad * 4 + r;
                const int m  = m0 + mrow;
                const int bb = m & 1;
                const int sg = m >> 1;
                const size_t ob = (((size_t)(bb * NHEADS + hblk) * SEQ) + sg) * HDIM;
                #pragma unroll
                for (int ni = 0; ni < 2; ++ni) {
                    const int i = ni * 16 + lrow;
                    const float2 sc = tab[(size_t)sg * 32 + i];
                    const float x1 = acc[mi][ni][r]     + bn[ni];
                    const float x2 = acc[mi][ni + 2][r] + bn[ni + 2];
                    // reference quirk: o2 = x1*sin - x2*cos
                    const float o1 = (x1 * sc.y - x2 * sc.x) * rope_scale;
                    const float o2 = (x1 * sc.x - x2 * sc.y) * rope_scale;
                    const u32 h1 = f2bf(o1);
                    const u32 h2 = f2bf(o2);
                    Oh[ob + i]      = (u16)h1;  Ol[ob + i]      = (u16)f2bf(o1 - bf2f(h1));
                    Oh[ob + i + 32] = (u16)h2;  Ol[ob + i + 32] = (u16)f2bf(o2 - bf2f(h2));
                }
            }
    } else if (mode == 1) {
        // split + transpose via LDS: vb[b][d][s_loc], stride 65 breaks banks
        __syncthreads();
        u32* vb = smem;    // 2*64*65 = 8320 u32 <= 12288
        #pragma unroll
        for (int mi = 0; mi < 2; ++mi)
            #pragma unroll
            for (int r = 0; r < 4; ++r) {
                const int mrow = w * 32 + mi * 16 + lquad * 4 + r;
                const int bb = mrow & 1;
                const int sl = mrow >> 1;
                #pragma unroll
                for (int ni = 0; ni < 4; ++ni) {
                    const int d = ni * 16 + lrow;
                    const float v = acc[mi][ni][r] + bn[ni];
                    const u32 hh = f2bf(v);
                    const u32 ll = f2bf(v - bf2f(hh));
                    vb[bb * 4160 + d * 65 + sl] = hh | (ll << 16);
                }
            }
        __syncthreads();
        const int hblk = nblk;
        #pragma unroll
        for (int rep = 0; rep < 4; ++rep) {
            const int c  = rep * 256 + tid;      // 1024 chunks
            const int bb = c >> 9;
            const int d  = (c >> 3) & 63;
            const int s8 = c & 7;
            u32 pk[8];
            #pragma unroll
            for (int j = 0; j < 8; ++j) pk[j] = vb[bb * 4160 + d * 65 + s8 * 8 + j];
            __align__(16) u16 hb[8];
            __align__(16) u16 lb[8];
            #pragma unroll
            for (int j = 0; j < 8; ++j) { hb[j] = (u16)pk[j]; lb[j] = (u16)(pk[j] >> 16); }
            const size_t ob = ((size_t)(bb * NHEADS + hblk) * HDIM + d) * SEQ + (m0 >> 1) + s8 * 8;
            *(uint4*)&Oh[ob] = *(const uint4*)hb;
            *(uint4*)&Ol[ob] = *(const uint4*)lb;
        }
    } else {
        #pragma unroll
        for (int mi = 0; mi < 2; ++mi)
            #pragma unroll
            for (int r = 0; r < 4; ++r) {
                const int m = m0 + w * 32 + mi * 16 + lquad * 4 + r;
                #pragma unroll
                for (int ni = 0; ni < 4; ++ni)
                    Of[(size_t)m * 1024 + n0 + ni * 16 + lrow] = acc[mi][ni][r] + bn[ni];
            }
    }
}

// Merged Q/K/V projection: blockIdx.z selects projection (0=Q,1=K,2=V).
// 1536 blocks -> ~3 resident blocks/CU (LDS-limited) vs 2 when separate.
__global__ __launch_bounds__(256) void qkv_gemm_kernel(
    const float* __restrict__ query, const float* __restrict__ key,
    const float* __restrict__ value,
    const u16* __restrict__ Wqh, const u16* __restrict__ Wql,
    const u16* __restrict__ Wkh, const u16* __restrict__ Wkl,
    const u16* __restrict__ Wvh, const u16* __restrict__ Wvl,
    const float* __restrict__ bq, const float* __restrict__ bk,
    const float* __restrict__ bv, const float2* __restrict__ tab,
    u16* __restrict__ Qh, u16* __restrict__ Ql,
    u16* __restrict__ Kh, u16* __restrict__ Kl,
    u16* __restrict__ VTh, u16* __restrict__ VTl)
{
    __shared__ uint4 smem4[3072];                 // 48 KB
    const int z  = blockIdx.z;
    const int id = blockIdx.x + 16 * blockIdx.y;  // 0..511 within slice
    const float* A  = (z == 0) ? query : (z == 1) ? key : value;
    const u16* Wh   = (z == 0) ? Wqh : (z == 1) ? Wkh : Wvh;
    const u16* Wl   = (z == 0) ? Wql : (z == 1) ? Wkl : Wvl;
    const float* bb = (z == 0) ? bq : (z == 1) ? bk : bv;
    u16* Oh = (z == 0) ? Qh : (z == 1) ? Kh : VTh;
    u16* Ol = (z == 0) ? Ql : (z == 1) ? Kl : VTl;
    const int mode = (z == 2) ? 1 : 0;
    const float scale = (z == 0) ? 0.125f : 1.0f;
    gemm_body<0>(id, mode, A, nullptr, nullptr, Wh, Wl, bb, tab, scale,
                 Oh, Ol, nullptr, (u32*)smem4);
}

// Final output projection: A = attn output (pre-split bf16), mode 2.
__global__ __launch_bounds__(256) void out_gemm_kernel(
    const u16* __restrict__ Ah, const u16* __restrict__ Al,
    const u16* __restrict__ Wh, const u16* __restrict__ Wl,
    const float* __restrict__ bias, float* __restrict__ Of)
{
    __shared__ uint4 smem4[3072];
    const int id = blockIdx.x + 16 * blockIdx.y;
    gemm_body<1>(id, 2, nullptr, Ah, Al, Wh, Wl, bias, nullptr, 1.0f,
                 nullptr, nullptr, Of, (u32*)smem4);
}

// ---------------------------------------------------------------------------
// MFMA flash attention, 32x32x16, split-bf16, no-max softmax, S^T/O^T form.
// Block = 256 threads (4 waves) = 128 q-rows; grid 512 (16 qt x 32 bh).
// Each K/V tile staged once per 128 q (half of R5's per-64q staging).
// S^T = K Q^T: P stays in registers; P^T B-frags via __shfl_xor(.,32).
// O^T = V^T P^T. LDS = 32 KB, XOR chunk-swizzled.
// ---------------------------------------------------------------------------
__global__ __launch_bounds__(256) void attn_mfma_kernel(
    const u16* __restrict__ Qh, const u16* __restrict__ Ql,
    const u16* __restrict__ Kh, const u16* __restrict__ Kl,
    const u16* __restrict__ Vh, const u16* __restrict__ Vl,
    u16* __restrict__ Oh, u16* __restrict__ Ol)
{
    __shared__ u16 sKh[4096], sKl[4096];   // [key][dh]  swizzled (8KB ea)
    __shared__ u16 sVh[4096], sVl[4096];   // [dh][key]  swizzled

    const int tid  = threadIdx.x;
    const int w    = tid >> 6;             // 0..3
    const int lane = tid & 63;
    const int l31  = lane & 31;
    const int g    = lane >> 5;

    // XCD-aware remap: 4 bh per XCD so K/V tiles are L2-local
    const int id = blockIdx.x + 16 * blockIdx.y;   // 0..511
    const int jj = id >> 3;                        // 0..63
    const int bh = ((id & 7) << 2) | (jj >> 4);
    const int qt = jj & 15;

    // Q B-frags (registers): col=q=l31, k = ks*16 + g*8 + j
    const size_t qg = ((size_t)bh * SEQ + qt * 128 + w * 32 + l31) * HDIM + g * 8;
    bfrag qfh[4], qfl[4];
    #pragma unroll
    for (int ks = 0; ks < 4; ++ks) {
        qfh[ks] = *(const bfrag*)&Qh[qg + ks * 16];
        qfl[ks] = *(const bfrag*)&Ql[qg + ks * 16];
    }

    // staging: wave w stages one of {sKh,sKl,sVh,sVl}, 8 gloads x 1KB
    const int srow   = lane >> 3;
    const int schunk = (lane & 7) ^ srow;
    const u16* gsrc; u16* lbase; size_t istep, ktstep;
    if (w < 2) {
        gsrc  = ((w == 0) ? Kh : Kl) + ((size_t)bh * SEQ + srow) * HDIM + schunk * 8;
        istep = 8 * 64; ktstep = 64 * 64;
        lbase = (w == 0) ? sKh : sKl;
    } else {
        gsrc  = ((w == 2) ? Vh : Vl) + ((size_t)bh * HDIM + srow) * SEQ + schunk * 8;
        istep = 8 * SEQ; ktstep = 64;
        lbase = (w == 2) ? sVh : sVl;
    }

    // frag offsets (u16 units): row-block a (32 rows), 16B chunk c of 8
    int koff[2][4];
    #pragma unroll
    for (int a = 0; a < 2; ++a) {
        const int row = a * 32 + l31;
        #pragma unroll
        for (int c = 0; c < 4; ++c)
            koff[a][c] = row * 64 + (((c * 2 + g) ^ (row & 7)) << 3);
    }

    f32x16 accO[2] = {};
    float l_loc = 0.0f;

    for (int kt = 0; kt < SEQ / 64; ++kt) {
        __syncthreads();
        const u16* gp = gsrc + (size_t)kt * ktstep;
        #pragma unroll
        for (int i = 0; i < 8; ++i)
            gload_lds16(gp + (size_t)i * istep, lbase + i * 512);
        __syncthreads();

        // ---- S^T = K Q^T (Q pre-scaled) : lane=q, regs=keys ----
        f32x16 accS[2] = {};
        #pragma unroll
        for (int kg = 0; kg < 2; ++kg)
            #pragma unroll
            for (int ks = 0; ks < 4; ++ks) {
                const bfrag kh = *(const bfrag*)&sKh[koff[kg][ks]];
                const bfrag kl = *(const bfrag*)&sKl[koff[kg][ks]];
                accS[kg] = __builtin_amdgcn_mfma_f32_32x32x16_bf16(kh, qfh[ks], accS[kg], 0, 0, 0);
                accS[kg] = __builtin_amdgcn_mfma_f32_32x32x16_bf16(kh, qfl[ks], accS[kg], 0, 0, 0);
                accS[kg] = __builtin_amdgcn_mfma_f32_32x32x16_bf16(kl, qfh[ks], accS[kg], 0, 0, 0);
            }

        // ---- p = exp(s): stays in registers (lane=q, reg=key) ----
        float pv[2][16];
        #pragma unroll
        for (int kg = 0; kg < 2; ++kg)
            #pragma unroll
            for (int r = 0; r < 16; ++r) {
                const float p = __expf(accS[kg][r]);
                pv[kg][r] = p;
                l_loc += p;
            }

        // ---- O^T += V^T P^T, P^T B-frags via g-half exchange ----
        #pragma unroll
        for (int kp = 0; kp < 4; ++kp) {
            const int kg = kp >> 1;
            const int c  = (kp & 1) * 8;
            float lo4[4], hi4[4];
            #pragma unroll
            for (int i = 0; i < 4; ++i) {
                const float a = pv[kg][c + i];        // keys j'=0..3 (held by g=0)
                const float b = pv[kg][c + 4 + i];    // keys j'=4..7 (held by g=1)
                const float own  = g ? b : a;
                const float send = g ? a : b;
                const float recv = __shfl_xor(send, 32);
                lo4[i] = g ? recv : own;
                hi4[i] = g ? own : recv;
            }
            fragu ph, pl;
            #pragma unroll
            for (int pr = 0; pr < 2; ++pr) {
                const u32 h0 = f2bf(lo4[2 * pr]);
                const u32 h1 = f2bf(lo4[2 * pr + 1]);
                ph.u[pr] = h0 | (h1 << 16);
                const u32 d0 = __float_as_uint(lo4[2 * pr]     - bf2f(h0));
                const u32 d1 = __float_as_uint(lo4[2 * pr + 1] - bf2f(h1));
                pl.u[pr] = (d0 >> 16) | (d1 & 0xffff0000u);
                const u32 h2 = f2bf(hi4[2 * pr]);
                const u32 h3 = f2bf(hi4[2 * pr + 1]);
                ph.u[2 + pr] = h2 | (h3 << 16);
                const u32 d2 = __float_as_uint(hi4[2 * pr]     - bf2f(h2));
                const u32 d3 = __float_as_uint(hi4[2 * pr + 1] - bf2f(h3));
                pl.u[2 + pr] = (d2 >> 16) | (d3 & 0xffff0000u);
            }
            #pragma unroll
            for (int dt = 0; dt < 2; ++dt) {
                const bfrag vh = *(const bfrag*)&sVh[koff[dt][kp]];
                const bfrag vl = *(const bfrag*)&sVl[koff[dt][kp]];
                accO[dt] = __builtin_amdgcn_mfma_f32_32x32x16_bf16(vh, ph.f, accO[dt], 0, 0, 0);
                accO[dt] = __builtin_amdgcn_mfma_f32_32x32x16_bf16(vh, pl.f, accO[dt], 0, 0, 0);
                accO[dt] = __builtin_amdgcn_mfma_f32_32x32x16_bf16(vl, ph.f, accO[dt], 0, 0, 0);
            }
        }
    }

    // ---- l: combine the two complementary g-halves, then write O ----
    const float inv = 1.0f / (l_loc + __shfl_xor(l_loc, 32));

    const int b = bh >> 4;
    const int h = bh & 15;
    const int sg = qt * 128 + w * 32 + l31;
    const size_t obase = ((size_t)sg * BATCH + b) * DMODEL + h * 64;
    #pragma unroll
    for (int dt = 0; dt < 2; ++dt)
        #pragma unroll
        for (int rq = 0; rq < 4; ++rq) {
            const int d0 = 8 * rq + 4 * g + 32 * dt;
            u32 hw[2], lw[2];
            #pragma unroll
            for (int pr = 0; pr < 2; ++pr) {
                const float v0 = accO[dt][rq * 4 + 2 * pr]     * inv;
                const float v1 = accO[dt][rq * 4 + 2 * pr + 1] * inv;
                const u32 h0 = f2bf(v0);
                const u32 h1 = f2bf(v1);
                hw[pr] = h0 | (h1 << 16);
                const u32 e0 = __float_as_uint(v0 - bf2f(h0));
                const u32 e1 = __float_as_uint(v1 - bf2f(h1));
                lw[pr] = (e0 >> 16) | (e1 & 0xffff0000u);
            }
            *(uint2*)&Oh[obase + d0] = make_uint2(hw[0], hw[1]);
            *(uint2*)&Ol[obase + d0] = make_uint2(lw[0], lw[1]);
        }
}

// ---------------------------------------------------------------------------
extern "C" void kernel_launch(void* const* d_in, const int* in_sizes, int n_in,
                              void* d_out, int out_size, void* d_ws, size_t ws_size,
                              hipStream_t stream)
{
    const float* query = (const float*)d_in[0];
    const float* key   = (const float*)d_in[1];
    const float* value = (const float*)d_in[2];
    const float* Wq    = (const float*)d_in[3];
    const float* bq    = (const float*)d_in[4];
    const float* Wk    = (const float*)d_in[5];
    const float* bk    = (const float*)d_in[6];
    const float* Wv    = (const float*)d_in[7];
    const float* bv    = (const float*)d_in[8];
    const float* Wo    = (const float*)d_in[9];
    const float* bo    = (const float*)d_in[10];
    float* out = (float*)d_out;

    // 64 MB workspace, time-multiplexed (MB offsets):
    //  Wq split [0,4), Wk [4,8), Wv [8,12), rope tab [12,12.5)  -- dead after QKV
    //  Qh [16,24) Ql [24,32) ; Kh [32,40) Kl [40,48) ; VTh [48,56) VTl [56,64)
    //  attn out split: AOh [0,8) AOl [8,16)   (w-splits + tab dead)
    //  Wo split [16,20)                        (Q dead after attn)
    char* wsb = (char*)d_ws;
    const size_t MB = 1024 * 1024;
    u16* Wqh = (u16*)(wsb + 0 * MB);  u16* Wql = (u16*)(wsb + 2 * MB);
    u16* Wkh = (u16*)(wsb + 4 * MB);  u16* Wkl = (u16*)(wsb + 6 * MB);
    u16* Wvh = (u16*)(wsb + 8 * MB);  u16* Wvl = (u16*)(wsb + 10 * MB);
    float2* tab = (float2*)(wsb + 12 * MB);
    u16* Qh  = (u16*)(wsb + 16 * MB); u16* Ql  = (u16*)(wsb + 24 * MB);
    u16* Kh  = (u16*)(wsb + 32 * MB); u16* Kl  = (u16*)(wsb + 40 * MB);
    u16* VTh = (u16*)(wsb + 48 * MB); u16* VTl = (u16*)(wsb + 56 * MB);
    u16* AOh = (u16*)(wsb + 0 * MB);  u16* AOl = (u16*)(wsb + 8 * MB);
    u16* Woh = (u16*)(wsb + 16 * MB); u16* Wol = (u16*)(wsb + 18 * MB);

    // weight splits + RoPE table
    prep_kernel<<<dim3(512, 4), 256, 0, stream>>>(Wq, Wk, Wv, Wqh, Wql, Wkh, Wkl, Wvh, Wvl, tab);
    // merged Q/K/V projections (+RoPE for Q/K; Q pre-scaled; V writes V^T)
    qkv_gemm_kernel<<<dim3(16, 32, 3), 256, 0, stream>>>(
        query, key, value, Wqh, Wql, Wkh, Wkl, Wvh, Wvl, bq, bk, bv, tab,
        Qh, Ql, Kh, Kl, VTh, VTl);
    // attention -> split bf16 (S,B,D)
    attn_mfma_kernel<<<dim3(16, 32), 256, 0, stream>>>(
        Qh, Ql, Kh, Kl, VTh, VTl, AOh, AOl);
    // output projection (A pre-split bf16)
    split_kernel<<<512, 256, 0, stream>>>(Wo, Woh, Wol);
    out_gemm_kernel<<<dim3(16, 32), 256, 0, stream>>>(AOh, AOl, Woh, Wol, bo, out);
}